// Round 1
// baseline (7271.950 us; speedup 1.0000x reference)
//
#include <hip/hip_runtime.h>

constexpr int kDepth = 6;
constexpr int kB = 8;
constexpr int kN = 1024;
constexpr int kDim = 768;
constexpr int kH = 12;
constexpr int kDh = 64;
constexpr int kMlp = 3072;
constexpr int kRows = kB * kN;   // 8192
constexpr int kQKV = 2304;       // q(768) k(768) v(768)

typedef __attribute__((ext_vector_type(4))) float f32x4;
typedef __attribute__((ext_vector_type(8))) short bf16x8;

__device__ __forceinline__ f32x4 mfma16x16x32(bf16x8 a, bf16x8 b, f32x4 c) {
  return __builtin_amdgcn_mfma_f32_16x16x32_bf16(a, b, c, 0, 0, 0);
}

__device__ __forceinline__ unsigned short f2bf(float f) {
  unsigned int u = __builtin_bit_cast(unsigned int, f);
  u = u + 0x7FFFu + ((u >> 16) & 1u);
  return (unsigned short)(u >> 16);
}

__device__ __forceinline__ void gload_lds16(const void* g, void* l) {
  __builtin_amdgcn_global_load_lds((__attribute__((address_space(1))) void*)g,
                                   (__attribute__((address_space(3))) void*)l,
                                   16, 0, 0);
}

// ---------------- LayerNorm: f32 in -> bf16 out ----------------
__global__ __launch_bounds__(256) void ln_kernel(const float* __restrict__ x,
                                                 const float* __restrict__ gamma,
                                                 const float* __restrict__ beta,
                                                 unsigned short* __restrict__ out) {
  int row = blockIdx.x, tid = threadIdx.x;
  const float* xr = x + (size_t)row * kDim;
  float v0 = xr[tid], v1 = xr[tid + 256], v2 = xr[tid + 512];
  float s = v0 + v1 + v2;
  float q = v0 * v0 + v1 * v1 + v2 * v2;
#pragma unroll
  for (int o = 32; o >= 1; o >>= 1) {
    s += __shfl_xor(s, o);
    q += __shfl_xor(q, o);
  }
  __shared__ float ss[4], sq[4];
  int wid = tid >> 6, lane = tid & 63;
  if (lane == 0) { ss[wid] = s; sq[wid] = q; }
  __syncthreads();
  s = ss[0] + ss[1] + ss[2] + ss[3];
  q = sq[0] + sq[1] + sq[2] + sq[3];
  float mean = s * (1.0f / kDim);
  float var = q * (1.0f / kDim) - mean * mean;
  float rstd = rsqrtf(var + 1e-5f);
  unsigned short* orow = out + (size_t)row * kDim;
  orow[tid]       = f2bf((v0 - mean) * rstd * gamma[tid]       + beta[tid]);
  orow[tid + 256] = f2bf((v1 - mean) * rstd * gamma[tid + 256] + beta[tid + 256]);
  orow[tid + 512] = f2bf((v2 - mean) * rstd * gamma[tid + 512] + beta[tid + 512]);
}

// ---------------- Weight transpose f32 [R,C] -> bf16 [C,R] ----------------
__global__ __launch_bounds__(256) void transpose_w(const float* __restrict__ in,
                                                   unsigned short* __restrict__ out,
                                                   int R, int C) {
  __shared__ float t[32][33];
  int tx = threadIdx.x & 31, ty = threadIdx.x >> 5;  // ty 0..7
  int c0 = blockIdx.x * 32, r0 = blockIdx.y * 32;
#pragma unroll
  for (int k = 0; k < 4; ++k) {
    int r = r0 + ty + k * 8;
    t[ty + k * 8][tx] = in[(size_t)r * C + c0 + tx];
  }
  __syncthreads();
#pragma unroll
  for (int k = 0; k < 4; ++k) {
    int c = c0 + ty + k * 8;
    out[(size_t)c * R + r0 + tx] = f2bf(t[tx][ty + k * 8]);
  }
}

// ---------------- V transpose: qkv[b,j,1536+g*64+d] -> vT[(b*12+g)*64+d][j] ----------------
__global__ __launch_bounds__(256) void transpose_v_kernel(const unsigned short* __restrict__ qkv,
                                                          unsigned short* __restrict__ vT) {
  __shared__ unsigned short t[32][33];
  int tx = threadIdx.x & 31, ty = threadIdx.x >> 5;
  int j0 = blockIdx.x * 32, d0 = blockIdx.y * 32;
  int bg = blockIdx.z;
  int b = bg / kH, g = bg % kH;
#pragma unroll
  for (int k = 0; k < 4; ++k) {
    int j = j0 + ty + k * 8;
    t[ty + k * 8][tx] = qkv[(size_t)(b * kN + j) * kQKV + 1536 + g * 64 + d0 + tx];
  }
  __syncthreads();
#pragma unroll
  for (int k = 0; k < 4; ++k) {
    int d = d0 + ty + k * 8;
    vT[((size_t)(b * kH + g) * kDh + d) * kN + j0 + tx] = t[tx][ty + k * 8];
  }
}

// ---------------- GEMM: A[M,K]bf16 x Bt[N,K]bf16 -> epilogue ----------------
// EPI 0: C=bf16 plain; EPI 1: bf16 gelu(acc+bias); EPI 2: resid = (acc+bias)*scl + resid (f32)
template <int EPI>
__global__ __launch_bounds__(256) void gemm_kernel(const unsigned short* __restrict__ A,
                                                   const unsigned short* __restrict__ Bt,
                                                   const float* __restrict__ bias,
                                                   const float* __restrict__ scl,
                                                   float* __restrict__ resid,
                                                   unsigned short* __restrict__ C,
                                                   int K, int ldc) {
  __shared__ __align__(16) unsigned short lA[128 * 64];
  __shared__ __align__(16) unsigned short lB[128 * 64];
  int tid = threadIdx.x, wid = tid >> 6, lane = tid & 63;
  int row0 = blockIdx.y * 128, col0 = blockIdx.x * 128;
  int wr = wid >> 1, wc = wid & 1;
  f32x4 zero = {0.f, 0.f, 0.f, 0.f};
  f32x4 acc[4][4];
#pragma unroll
  for (int m = 0; m < 4; ++m)
#pragma unroll
    for (int n = 0; n < 4; ++n) acc[m][n] = zero;

  for (int kt = 0; kt < K; kt += 64) {
    __syncthreads();
#pragma unroll
    for (int t = 0; t < 4; ++t) {
      int cbase = wid * 256 + t * 64;
      int c = cbase + lane;
      int r = c >> 3, slot = c & 7;
      int k8 = slot ^ (r & 7);  // source-swizzle so LDS holds XOR-swizzled layout
      gload_lds16(&A[(size_t)(row0 + r) * K + kt + k8 * 8], &lA[cbase * 8]);
      gload_lds16(&Bt[(size_t)(col0 + r) * K + kt + k8 * 8], &lB[cbase * 8]);
    }
    __syncthreads();
#pragma unroll
    for (int kk = 0; kk < 2; ++kk) {
      bf16x8 af[4], bfr[4];
      int kslot = kk * 4 + (lane >> 4);
#pragma unroll
      for (int m = 0; m < 4; ++m) {
        int r = wr * 64 + m * 16 + (lane & 15);
        af[m] = *reinterpret_cast<const bf16x8*>(&lA[r * 64 + ((kslot ^ (r & 7)) << 3)]);
      }
#pragma unroll
      for (int n = 0; n < 4; ++n) {
        int r = wc * 64 + n * 16 + (lane & 15);
        bfr[n] = *reinterpret_cast<const bf16x8*>(&lB[r * 64 + ((kslot ^ (r & 7)) << 3)]);
      }
#pragma unroll
      for (int m = 0; m < 4; ++m)
#pragma unroll
        for (int n = 0; n < 4; ++n) acc[m][n] = mfma16x16x32(af[m], bfr[n], acc[m][n]);
    }
  }
#pragma unroll
  for (int m = 0; m < 4; ++m)
#pragma unroll
    for (int n = 0; n < 4; ++n)
#pragma unroll
      for (int r4 = 0; r4 < 4; ++r4) {
        int row = row0 + wr * 64 + m * 16 + ((lane >> 4) << 2) + r4;
        int col = col0 + wc * 64 + n * 16 + (lane & 15);
        float v = acc[m][n][r4];
        if (EPI == 0) {
          C[(size_t)row * ldc + col] = f2bf(v);
        } else if (EPI == 1) {
          v += bias[col];
          v = 0.5f * v * (1.f + erff(v * 0.70710678118654752f));
          C[(size_t)row * ldc + col] = f2bf(v);
        } else {
          v = (v + bias[col]) * scl[col];
          size_t idx = (size_t)row * kDim + col;
          resid[idx] = resid[idx] + v;
        }
      }
}

// ---------------- QK^T * scale + mix_pre -> dots f32 ----------------
__global__ __launch_bounds__(256) void dots_kernel(const unsigned short* __restrict__ qkv,
                                                   const float* __restrict__ pre,
                                                   float* __restrict__ dots,
                                                   int i0, int IC) {
  __shared__ float s[kH][32][33];
  __shared__ float spre[144];
  int tid = threadIdx.x, wid = tid >> 6, lane = tid & 63;
  if (tid < 144) spre[tid] = pre[tid];
  int j0 = blockIdx.x * 32;
  int il0 = blockIdx.y * 32;
  int b = blockIdx.z;
  f32x4 zero = {0.f, 0.f, 0.f, 0.f};
#pragma unroll
  for (int rep = 0; rep < 3; ++rep) {
    int h = rep * 4 + wid;
    f32x4 acc[2][2];
    acc[0][0] = zero; acc[0][1] = zero; acc[1][0] = zero; acc[1][1] = zero;
#pragma unroll
    for (int kk = 0; kk < 2; ++kk) {
      bf16x8 aq[2], bk[2];
#pragma unroll
      for (int m = 0; m < 2; ++m) {
        int tok = i0 + il0 + m * 16 + (lane & 15);
        aq[m] = *reinterpret_cast<const bf16x8*>(
            &qkv[(size_t)(b * kN + tok) * kQKV + h * 64 + kk * 32 + ((lane >> 4) << 3)]);
      }
#pragma unroll
      for (int n = 0; n < 2; ++n) {
        int tj = j0 + n * 16 + (lane & 15);
        bk[n] = *reinterpret_cast<const bf16x8*>(
            &qkv[(size_t)(b * kN + tj) * kQKV + 768 + h * 64 + kk * 32 + ((lane >> 4) << 3)]);
      }
#pragma unroll
      for (int m = 0; m < 2; ++m)
#pragma unroll
        for (int n = 0; n < 2; ++n) acc[m][n] = mfma16x16x32(aq[m], bk[n], acc[m][n]);
    }
#pragma unroll
    for (int m = 0; m < 2; ++m)
#pragma unroll
      for (int n = 0; n < 2; ++n)
#pragma unroll
        for (int r = 0; r < 4; ++r)
          s[h][m * 16 + ((lane >> 4) << 2) + r][n * 16 + (lane & 15)] = acc[m][n][r] * 0.125f;
  }
  __syncthreads();
#pragma unroll
  for (int p = 0; p < 4; ++p) {
    int pos = tid + p * 256;
    int ii = pos >> 5, jj = pos & 31;
    float sh[kH];
#pragma unroll
    for (int h = 0; h < kH; ++h) sh[h] = s[h][ii][jj];
#pragma unroll
    for (int g = 0; g < kH; ++g) {
      float o = 0.f;
#pragma unroll
      for (int h = 0; h < kH; ++h) o += sh[h] * spre[h * 12 + g];
      dots[((size_t)(b * kH + g) * IC + il0 + ii) * kN + j0 + jj] = o;
    }
  }
}

// ---------------- softmax over j (per head) + mix_post -> p bf16 ----------------
__global__ __launch_bounds__(256) void softmax_mix_kernel(const float* __restrict__ dots,
                                                          const float* __restrict__ post,
                                                          unsigned short* __restrict__ pbuf,
                                                          int IC) {
  __shared__ float row[kH][kN];
  __shared__ float mg[kH], lg[kH];
  __shared__ float spost[144];
  int tid = threadIdx.x, wid = tid >> 6, lane = tid & 63;
  int i = blockIdx.x, b = blockIdx.y;
  if (tid < 144) spost[tid] = post[tid];
  for (int g = 0; g < kH; ++g)
    for (int j = tid; j < kN; j += 256)
      row[g][j] = dots[((size_t)(b * kH + g) * IC + i) * kN + j];
  __syncthreads();
  for (int rep = 0; rep < 3; ++rep) {
    int g = rep * 4 + wid;
    float m = -1e30f;
    for (int j = lane; j < kN; j += 64) m = fmaxf(m, row[g][j]);
#pragma unroll
    for (int o = 32; o >= 1; o >>= 1) m = fmaxf(m, __shfl_xor(m, o));
    float sum = 0.f;
    for (int j = lane; j < kN; j += 64) sum += __expf(row[g][j] - m);
#pragma unroll
    for (int o = 32; o >= 1; o >>= 1) sum += __shfl_xor(sum, o);
    if (lane == 0) { mg[g] = m; lg[g] = 1.f / sum; }
  }
  __syncthreads();
  for (int idx = tid; idx < kH * kN; idx += 256) {
    int g = idx >> 10, j = idx & (kN - 1);
    row[g][j] = __expf(row[g][j] - mg[g]) * lg[g];
  }
  __syncthreads();
  for (int j = tid; j < kN; j += 256) {
    float a[kH];
#pragma unroll
    for (int h = 0; h < kH; ++h) a[h] = row[h][j];
#pragma unroll
    for (int g2 = 0; g2 < kH; ++g2) {
      float o = 0.f;
#pragma unroll
      for (int h = 0; h < kH; ++h) o += a[h] * spost[h * 12 + g2];
      pbuf[((size_t)(b * kH + g2) * IC + i) * kN + j] = f2bf(o);
    }
  }
}

// ---------------- PV: out[b,i,g*64+d] = sum_j p[b,g,i,j] * v[b,g,j,d] ----------------
__global__ __launch_bounds__(256) void pv_kernel(const unsigned short* __restrict__ pbuf,
                                                 const unsigned short* __restrict__ vT,
                                                 unsigned short* __restrict__ attn_out,
                                                 int i0, int IC) {
  int tid = threadIdx.x, wid = tid >> 6, lane = tid & 63;
  int i16 = blockIdx.x * 16;
  int g = blockIdx.y, b = blockIdx.z;
  const unsigned short* prow = pbuf + (size_t)(b * kH + g) * IC * kN;
  const unsigned short* vrow = vT + (size_t)(b * kH + g) * kDh * kN;
  f32x4 zero = {0.f, 0.f, 0.f, 0.f};
  f32x4 acc[4];
  acc[0] = zero; acc[1] = zero; acc[2] = zero; acc[3] = zero;
  int il = i16 + (lane & 15);
#pragma unroll
  for (int s = 0; s < 8; ++s) {
    int kt = (wid * 8 + s) * 32 + ((lane >> 4) << 3);
    bf16x8 ap = *reinterpret_cast<const bf16x8*>(&prow[(size_t)il * kN + kt]);
#pragma unroll
    for (int n = 0; n < 4; ++n) {
      int d = n * 16 + (lane & 15);
      bf16x8 bv = *reinterpret_cast<const bf16x8*>(&vrow[(size_t)d * kN + kt]);
      acc[n] = mfma16x16x32(ap, bv, acc[n]);
    }
  }
  __shared__ float red[3][16][64];
  if (wid > 0) {
#pragma unroll
    for (int n = 0; n < 4; ++n)
#pragma unroll
      for (int r = 0; r < 4; ++r)
        red[wid - 1][((lane >> 4) << 2) + r][n * 16 + (lane & 15)] = acc[n][r];
  }
  __syncthreads();
  if (wid == 0) {
#pragma unroll
    for (int n = 0; n < 4; ++n)
#pragma unroll
      for (int r = 0; r < 4; ++r) {
        int rr = ((lane >> 4) << 2) + r, cc = n * 16 + (lane & 15);
        float v = acc[n][r] + red[0][rr][cc] + red[1][rr][cc] + red[2][rr][cc];
        int tok = i0 + i16 + rr;
        attn_out[(size_t)(b * kN + tok) * kDim + g * kDh + cc] = f2bf(v);
      }
  }
}

extern "C" void kernel_launch(void* const* d_in, const int* in_sizes, int n_in,
                              void* d_out, int out_size, void* d_ws, size_t ws_size,
                              hipStream_t stream) {
  (void)in_sizes; (void)n_in; (void)out_size;
  const float* x     = (const float*)d_in[0];
  const float* ln1_g = (const float*)d_in[1];
  const float* ln1_b = (const float*)d_in[2];
  const float* Wq    = (const float*)d_in[3];
  const float* Wkv   = (const float*)d_in[4];
  const float* pre   = (const float*)d_in[5];
  const float* post  = (const float*)d_in[6];
  const float* Wo    = (const float*)d_in[7];
  const float* bo    = (const float*)d_in[8];
  const float* s1    = (const float*)d_in[9];
  const float* ln2_g = (const float*)d_in[10];
  const float* ln2_b = (const float*)d_in[11];
  const float* W1    = (const float*)d_in[12];
  const float* b1    = (const float*)d_in[13];
  const float* W2    = (const float*)d_in[14];
  const float* b2    = (const float*)d_in[15];
  const float* s2    = (const float*)d_in[16];
  float* xo = (float*)d_out;

  char* ws = (char*)d_ws;
  size_t off = 0;
  auto alloc = [&](size_t bytes) -> void* {
    void* p = ws + off;
    off += (bytes + 255) & ~(size_t)255;
    return p;
  };
  unsigned short* h_buf   = (unsigned short*)alloc((size_t)kRows * kDim * 2);
  unsigned short* qkv     = (unsigned short*)alloc((size_t)kRows * kQKV * 2);
  unsigned short* vT      = (unsigned short*)alloc((size_t)kB * kH * kDh * kN * 2);
  unsigned short* attnout = (unsigned short*)alloc((size_t)kRows * kDim * 2);
  unsigned short* mid     = (unsigned short*)alloc((size_t)kRows * kMlp * 2);
  unsigned short* wqT     = (unsigned short*)alloc((size_t)kDim * kDim * 2);
  unsigned short* wkvT    = (unsigned short*)alloc((size_t)2 * kDim * kDim * 2);
  unsigned short* woT     = (unsigned short*)alloc((size_t)kDim * kDim * 2);
  unsigned short* w1T     = (unsigned short*)alloc((size_t)kMlp * kDim * 2);
  unsigned short* w2T     = (unsigned short*)alloc((size_t)kDim * kMlp * 2);

  size_t base = off;
  int IC = 1024;
  while (IC > 32 && base + (size_t)(kB * kH) * IC * kN * 6 + 1024 > ws_size) IC >>= 1;
  float* dots          = (float*)alloc((size_t)(kB * kH) * IC * kN * 4);
  unsigned short* pbuf = (unsigned short*)alloc((size_t)(kB * kH) * IC * kN * 2);

  hipMemcpyAsync(xo, x, (size_t)kRows * kDim * 4, hipMemcpyDeviceToDevice, stream);

  for (int L = 0; L < kDepth; ++L) {
    // --- attention block ---
    ln_kernel<<<kRows, 256, 0, stream>>>(xo, ln1_g + L * kDim, ln1_b + L * kDim, h_buf);
    transpose_w<<<dim3(kDim / 32, kDim / 32), 256, 0, stream>>>(
        Wq + (size_t)L * kDim * kDim, wqT, kDim, kDim);
    transpose_w<<<dim3(2 * kDim / 32, kDim / 32), 256, 0, stream>>>(
        Wkv + (size_t)L * kDim * 2 * kDim, wkvT, kDim, 2 * kDim);
    transpose_w<<<dim3(kDim / 32, kDim / 32), 256, 0, stream>>>(
        Wo + (size_t)L * kDim * kDim, woT, kDim, kDim);
    transpose_w<<<dim3(kMlp / 32, kDim / 32), 256, 0, stream>>>(
        W1 + (size_t)L * kDim * kMlp, w1T, kDim, kMlp);
    transpose_w<<<dim3(kDim / 32, kMlp / 32), 256, 0, stream>>>(
        W2 + (size_t)L * kMlp * kDim, w2T, kMlp, kDim);

    gemm_kernel<0><<<dim3(kDim / 128, kRows / 128), 256, 0, stream>>>(
        h_buf, wqT, nullptr, nullptr, nullptr, qkv, kDim, kQKV);
    gemm_kernel<0><<<dim3(2 * kDim / 128, kRows / 128), 256, 0, stream>>>(
        h_buf, wkvT, nullptr, nullptr, nullptr, qkv + kDim, kDim, kQKV);
    transpose_v_kernel<<<dim3(kN / 32, kDh / 32, kB * kH), 256, 0, stream>>>(qkv, vT);

    for (int i0 = 0; i0 < kN; i0 += IC) {
      dots_kernel<<<dim3(kN / 32, IC / 32, kB), 256, 0, stream>>>(
          qkv, pre + L * 144, dots, i0, IC);
      softmax_mix_kernel<<<dim3(IC, kB), 256, 0, stream>>>(
          dots, post + L * 144, pbuf, IC);
      pv_kernel<<<dim3(IC / 16, kH, kB), 256, 0, stream>>>(pbuf, vT, attnout, i0, IC);
    }
    gemm_kernel<2><<<dim3(kDim / 128, kRows / 128), 256, 0, stream>>>(
        attnout, woT, bo + L * kDim, s1 + L * kDim, xo, nullptr, kDim, kDim);

    // --- MLP block ---
    ln_kernel<<<kRows, 256, 0, stream>>>(xo, ln2_g + L * kDim, ln2_b + L * kDim, h_buf);
    gemm_kernel<1><<<dim3(kMlp / 128, kRows / 128), 256, 0, stream>>>(
        h_buf, w1T, b1 + L * kMlp, nullptr, nullptr, mid, kDim, kMlp);
    gemm_kernel<2><<<dim3(kDim / 128, kRows / 128), 256, 0, stream>>>(
        mid, w2T, b2 + L * kDim, s2 + L * kDim, xo, nullptr, kMlp, kDim);
  }
}

// Round 4
// 6249.299 us; speedup vs baseline: 1.1636x; 1.1636x over previous
//
#include <hip/hip_runtime.h>

constexpr int kDepth = 6;
constexpr int kB = 8;
constexpr int kN = 1024;
constexpr int kDim = 768;
constexpr int kH = 12;
constexpr int kDh = 64;
constexpr int kMlp = 3072;
constexpr int kRows = kB * kN;   // 8192
constexpr int kQKV = 2304;       // q(768) k(768) v(768)

typedef __attribute__((ext_vector_type(4))) float f32x4;
typedef __attribute__((ext_vector_type(8))) short bf16x8;

__device__ __forceinline__ f32x4 mfma16x16x32(bf16x8 a, bf16x8 b, f32x4 c) {
  return __builtin_amdgcn_mfma_f32_16x16x32_bf16(a, b, c, 0, 0, 0);
}

__device__ __forceinline__ unsigned short f2bf(float f) {
  unsigned int u = __builtin_bit_cast(unsigned int, f);
  u = u + 0x7FFFu + ((u >> 16) & 1u);
  return (unsigned short)(u >> 16);
}

__device__ __forceinline__ float bf2f(unsigned short u) {
  return __builtin_bit_cast(float, (unsigned int)u << 16);
}

__device__ __forceinline__ void gload_lds16(const void* g, void* l) {
  __builtin_amdgcn_global_load_lds((__attribute__((address_space(1))) void*)g,
                                   (__attribute__((address_space(3))) void*)l,
                                   16, 0, 0);
}

// ---------------- LayerNorm: f32 in -> bf16 out ----------------
__global__ __launch_bounds__(256) void ln_kernel(const float* __restrict__ x,
                                                 const float* __restrict__ gamma,
                                                 const float* __restrict__ beta,
                                                 unsigned short* __restrict__ out) {
  int row = blockIdx.x, tid = threadIdx.x;
  const float* xr = x + (size_t)row * kDim;
  float v0 = xr[tid], v1 = xr[tid + 256], v2 = xr[tid + 512];
  float s = v0 + v1 + v2;
  float q = v0 * v0 + v1 * v1 + v2 * v2;
#pragma unroll
  for (int o = 32; o >= 1; o >>= 1) {
    s += __shfl_xor(s, o);
    q += __shfl_xor(q, o);
  }
  __shared__ float ss[4], sq[4];
  int wid = tid >> 6, lane = tid & 63;
  if (lane == 0) { ss[wid] = s; sq[wid] = q; }
  __syncthreads();
  s = ss[0] + ss[1] + ss[2] + ss[3];
  q = sq[0] + sq[1] + sq[2] + sq[3];
  float mean = s * (1.0f / kDim);
  float var = q * (1.0f / kDim) - mean * mean;
  float rstd = rsqrtf(var + 1e-5f);
  unsigned short* orow = out + (size_t)row * kDim;
  orow[tid]       = f2bf((v0 - mean) * rstd * gamma[tid]       + beta[tid]);
  orow[tid + 256] = f2bf((v1 - mean) * rstd * gamma[tid + 256] + beta[tid + 256]);
  orow[tid + 512] = f2bf((v2 - mean) * rstd * gamma[tid + 512] + beta[tid + 512]);
}

// ---------------- Weight transpose f32 [R,C] -> bf16 [C,R] ----------------
__global__ __launch_bounds__(256) void transpose_w(const float* __restrict__ in,
                                                   unsigned short* __restrict__ out,
                                                   int R, int C) {
  __shared__ float t[32][33];
  int tx = threadIdx.x & 31, ty = threadIdx.x >> 5;  // ty 0..7
  int c0 = blockIdx.x * 32, r0 = blockIdx.y * 32;
#pragma unroll
  for (int k = 0; k < 4; ++k) {
    int r = r0 + ty + k * 8;
    t[ty + k * 8][tx] = in[(size_t)r * C + c0 + tx];
  }
  __syncthreads();
#pragma unroll
  for (int k = 0; k < 4; ++k) {
    int c = c0 + ty + k * 8;
    out[(size_t)c * R + r0 + tx] = f2bf(t[tx][ty + k * 8]);
  }
}

// ---------------- V transpose: qkv[b,j,1536+g*64+d] -> vT[(b*12+g)*64+d][j] ----------------
__global__ __launch_bounds__(256) void transpose_v_kernel(const unsigned short* __restrict__ qkv,
                                                          unsigned short* __restrict__ vT) {
  __shared__ unsigned short t[32][33];
  int tx = threadIdx.x & 31, ty = threadIdx.x >> 5;
  int j0 = blockIdx.x * 32, d0 = blockIdx.y * 32;
  int bg = blockIdx.z;
  int b = bg / kH, g = bg % kH;
#pragma unroll
  for (int k = 0; k < 4; ++k) {
    int j = j0 + ty + k * 8;
    t[ty + k * 8][tx] = qkv[(size_t)(b * kN + j) * kQKV + 1536 + g * 64 + d0 + tx];
  }
  __syncthreads();
#pragma unroll
  for (int k = 0; k < 4; ++k) {
    int d = d0 + ty + k * 8;
    vT[((size_t)(b * kH + g) * kDh + d) * kN + j0 + tx] = t[tx][ty + k * 8];
  }
}

// ---------------- GEMM: A[M,K]bf16 x Bt[N,K]bf16 -> epilogue ----------------
// EPI 0: C=bf16 plain; EPI 1: bf16 gelu(acc+bias); EPI 2: resid = (acc+bias)*scl + resid (f32)
template <int EPI>
__global__ __launch_bounds__(256) void gemm_kernel(const unsigned short* __restrict__ A,
                                                   const unsigned short* __restrict__ Bt,
                                                   const float* __restrict__ bias,
                                                   const float* __restrict__ scl,
                                                   float* __restrict__ resid,
                                                   unsigned short* __restrict__ C,
                                                   int K, int ldc) {
  __shared__ __align__(16) unsigned short lA[128 * 64];
  __shared__ __align__(16) unsigned short lB[128 * 64];
  int tid = threadIdx.x, wid = tid >> 6, lane = tid & 63;
  // XCD-aware bijective chunked swizzle (all grids have nwg % 8 == 0)
  int gx = gridDim.x;
  int nwg = gx * gridDim.y;
  int orig = blockIdx.y * gx + blockIdx.x;
  int chunk = nwg >> 3;
  int wg = (orig & 7) * chunk + (orig >> 3);
  int bx = wg % gx, by = wg / gx;
  int row0 = by * 128, col0 = bx * 128;
  int wr = wid >> 1, wc = wid & 1;
  f32x4 zero = {0.f, 0.f, 0.f, 0.f};
  f32x4 acc[4][4];
#pragma unroll
  for (int m = 0; m < 4; ++m)
#pragma unroll
    for (int n = 0; n < 4; ++n) acc[m][n] = zero;

  for (int kt = 0; kt < K; kt += 64) {
    __syncthreads();
#pragma unroll
    for (int t = 0; t < 4; ++t) {
      int cbase = wid * 256 + t * 64;
      int c = cbase + lane;
      int r = c >> 3, slot = c & 7;
      int k8 = slot ^ (r & 7);  // source-swizzle so LDS holds XOR-swizzled layout
      gload_lds16(&A[(size_t)(row0 + r) * K + kt + k8 * 8], &lA[cbase * 8]);
      gload_lds16(&Bt[(size_t)(col0 + r) * K + kt + k8 * 8], &lB[cbase * 8]);
    }
    __syncthreads();
#pragma unroll
    for (int kk = 0; kk < 2; ++kk) {
      bf16x8 af[4], bfr[4];
      int kslot = kk * 4 + (lane >> 4);
#pragma unroll
      for (int m = 0; m < 4; ++m) {
        int r = wr * 64 + m * 16 + (lane & 15);
        af[m] = *reinterpret_cast<const bf16x8*>(&lA[r * 64 + ((kslot ^ (r & 7)) << 3)]);
      }
#pragma unroll
      for (int n = 0; n < 4; ++n) {
        int r = wc * 64 + n * 16 + (lane & 15);
        bfr[n] = *reinterpret_cast<const bf16x8*>(&lB[r * 64 + ((kslot ^ (r & 7)) << 3)]);
      }
#pragma unroll
      for (int m = 0; m < 4; ++m)
#pragma unroll
        for (int n = 0; n < 4; ++n) acc[m][n] = mfma16x16x32(af[m], bfr[n], acc[m][n]);
    }
  }
#pragma unroll
  for (int m = 0; m < 4; ++m)
#pragma unroll
    for (int n = 0; n < 4; ++n)
#pragma unroll
      for (int r4 = 0; r4 < 4; ++r4) {
        int row = row0 + wr * 64 + m * 16 + ((lane >> 4) << 2) + r4;
        int col = col0 + wc * 64 + n * 16 + (lane & 15);
        float v = acc[m][n][r4];
        if (EPI == 0) {
          C[(size_t)row * ldc + col] = f2bf(v);
        } else if (EPI == 1) {
          v += bias[col];
          v = 0.5f * v * (1.f + erff(v * 0.70710678118654752f));
          C[(size_t)row * ldc + col] = f2bf(v);
        } else {
          v = (v + bias[col]) * scl[col];
          size_t idx = (size_t)row * kDim + col;
          resid[idx] = resid[idx] + v;
        }
      }
}

// ---------------- QK^T * scale + mix_pre -> dots bf16 ----------------
__global__ __launch_bounds__(256) void dots_kernel(const unsigned short* __restrict__ qkv,
                                                   const float* __restrict__ pre,
                                                   unsigned short* __restrict__ dots,
                                                   int i0, int IC) {
  __shared__ float s[kH][32][33];
  __shared__ float spre[144];
  int tid = threadIdx.x, wid = tid >> 6, lane = tid & 63;
  if (tid < 144) spre[tid] = pre[tid];
  int j0 = blockIdx.x * 32;
  int il0 = blockIdx.y * 32;
  int b = blockIdx.z;
  f32x4 zero = {0.f, 0.f, 0.f, 0.f};
#pragma unroll
  for (int rep = 0; rep < 3; ++rep) {
    int h = rep * 4 + wid;
    f32x4 acc[2][2];
    acc[0][0] = zero; acc[0][1] = zero; acc[1][0] = zero; acc[1][1] = zero;
#pragma unroll
    for (int kk = 0; kk < 2; ++kk) {
      bf16x8 aq[2], bk[2];
#pragma unroll
      for (int m = 0; m < 2; ++m) {
        int tok = i0 + il0 + m * 16 + (lane & 15);
        aq[m] = *reinterpret_cast<const bf16x8*>(
            &qkv[(size_t)(b * kN + tok) * kQKV + h * 64 + kk * 32 + ((lane >> 4) << 3)]);
      }
#pragma unroll
      for (int n = 0; n < 2; ++n) {
        int tj = j0 + n * 16 + (lane & 15);
        bk[n] = *reinterpret_cast<const bf16x8*>(
            &qkv[(size_t)(b * kN + tj) * kQKV + 768 + h * 64 + kk * 32 + ((lane >> 4) << 3)]);
      }
#pragma unroll
      for (int m = 0; m < 2; ++m)
#pragma unroll
        for (int n = 0; n < 2; ++n) acc[m][n] = mfma16x16x32(aq[m], bk[n], acc[m][n]);
    }
#pragma unroll
    for (int m = 0; m < 2; ++m)
#pragma unroll
      for (int n = 0; n < 2; ++n)
#pragma unroll
        for (int r = 0; r < 4; ++r)
          s[h][m * 16 + ((lane >> 4) << 2) + r][n * 16 + (lane & 15)] = acc[m][n][r] * 0.125f;
  }
  __syncthreads();
#pragma unroll
  for (int p = 0; p < 4; ++p) {
    int pos = tid + p * 256;
    int ii = pos >> 5, jj = pos & 31;
    float sh[kH];
#pragma unroll
    for (int h = 0; h < kH; ++h) sh[h] = s[h][ii][jj];
#pragma unroll
    for (int g = 0; g < kH; ++g) {
      float o = 0.f;
#pragma unroll
      for (int h = 0; h < kH; ++h) o += sh[h] * spre[h * 12 + g];
      dots[((size_t)(b * kH + g) * IC + il0 + ii) * kN + j0 + jj] = f2bf(o);
    }
  }
}

// ---------------- softmax over j (per head, no-max + clamp) + mix_post -> p bf16 ----------------
__global__ __launch_bounds__(256) void softmax_mix_kernel(const unsigned short* __restrict__ dots,
                                                          const float* __restrict__ post,
                                                          unsigned short* __restrict__ pbuf,
                                                          int IC) {
  __shared__ float row[kH][kN];
  __shared__ float lg[kH];
  __shared__ float spost[144];
  int tid = threadIdx.x, wid = tid >> 6, lane = tid & 63;
  int i = blockIdx.x, b = blockIdx.y;
  if (tid < 144) spost[tid] = post[tid];
  for (int g = 0; g < kH; ++g)
    for (int j = tid; j < kN; j += 256) {
      float sv = bf2f(dots[((size_t)(b * kH + g) * IC + i) * kN + j]);
      row[g][j] = __expf(fminf(fmaxf(sv, -15.f), 15.f));
    }
  __syncthreads();
  for (int rep = 0; rep < 3; ++rep) {
    int g = rep * 4 + wid;
    float sum = 0.f;
    for (int j = lane; j < kN; j += 64) sum += row[g][j];
#pragma unroll
    for (int o = 32; o >= 1; o >>= 1) sum += __shfl_xor(sum, o);
    if (lane == 0) lg[g] = 1.f / sum;
  }
  __syncthreads();
  for (int j = tid; j < kN; j += 256) {
    float a[kH];
#pragma unroll
    for (int h = 0; h < kH; ++h) a[h] = row[h][j] * lg[h];
#pragma unroll
    for (int g2 = 0; g2 < kH; ++g2) {
      float o = 0.f;
#pragma unroll
      for (int h = 0; h < kH; ++h) o += a[h] * spost[h * 12 + g2];
      pbuf[((size_t)(b * kH + g2) * IC + i) * kN + j] = f2bf(o);
    }
  }
}

// ---------------- PV: out[b,i,g*64+d] = sum_j p[b,g,i,j] * v[b,g,j,d] ----------------
__global__ __launch_bounds__(256) void pv_kernel(const unsigned short* __restrict__ pbuf,
                                                 const unsigned short* __restrict__ vT,
                                                 unsigned short* __restrict__ attn_out,
                                                 int i0, int IC) {
  int tid = threadIdx.x, wid = tid >> 6, lane = tid & 63;
  int i16 = blockIdx.x * 16;
  int g = blockIdx.y, b = blockIdx.z;
  const unsigned short* prow = pbuf + (size_t)(b * kH + g) * IC * kN;
  const unsigned short* vrow = vT + (size_t)(b * kH + g) * kDh * kN;
  f32x4 zero = {0.f, 0.f, 0.f, 0.f};
  f32x4 acc[4];
  acc[0] = zero; acc[1] = zero; acc[2] = zero; acc[3] = zero;
  int il = i16 + (lane & 15);
#pragma unroll
  for (int s = 0; s < 8; ++s) {
    int kt = (wid * 8 + s) * 32 + ((lane >> 4) << 3);
    bf16x8 ap = *reinterpret_cast<const bf16x8*>(&prow[(size_t)il * kN + kt]);
#pragma unroll
    for (int n = 0; n < 4; ++n) {
      int d = n * 16 + (lane & 15);
      bf16x8 bv = *reinterpret_cast<const bf16x8*>(&vrow[(size_t)d * kN + kt]);
      acc[n] = mfma16x16x32(ap, bv, acc[n]);
    }
  }
  __shared__ float red[3][16][64];
  if (wid > 0) {
#pragma unroll
    for (int n = 0; n < 4; ++n)
#pragma unroll
      for (int r = 0; r < 4; ++r)
        red[wid - 1][((lane >> 4) << 2) + r][n * 16 + (lane & 15)] = acc[n][r];
  }
  __syncthreads();
  if (wid == 0) {
#pragma unroll
    for (int n = 0; n < 4; ++n)
#pragma unroll
      for (int r = 0; r < 4; ++r) {
        int rr = ((lane >> 4) << 2) + r, cc = n * 16 + (lane & 15);
        float v = acc[n][r] + red[0][rr][cc] + red[1][rr][cc] + red[2][rr][cc];
        int tok = i0 + i16 + rr;
        attn_out[(size_t)(b * kN + tok) * kDim + g * kDh + cc] = f2bf(v);
      }
  }
}

extern "C" void kernel_launch(void* const* d_in, const int* in_sizes, int n_in,
                              void* d_out, int out_size, void* d_ws, size_t ws_size,
                              hipStream_t stream) {
  (void)in_sizes; (void)n_in; (void)out_size;
  const float* x     = (const float*)d_in[0];
  const float* ln1_g = (const float*)d_in[1];
  const float* ln1_b = (const float*)d_in[2];
  const float* Wq    = (const float*)d_in[3];
  const float* Wkv   = (const float*)d_in[4];
  const float* pre   = (const float*)d_in[5];
  const float* post  = (const float*)d_in[6];
  const float* Wo    = (const float*)d_in[7];
  const float* bo    = (const float*)d_in[8];
  const float* s1    = (const float*)d_in[9];
  const float* ln2_g = (const float*)d_in[10];
  const float* ln2_b = (const float*)d_in[11];
  const float* W1    = (const float*)d_in[12];
  const float* b1    = (const float*)d_in[13];
  const float* W2    = (const float*)d_in[14];
  const float* b2    = (const float*)d_in[15];
  const float* s2    = (const float*)d_in[16];
  float* xo = (float*)d_out;

  char* ws = (char*)d_ws;
  size_t off = 0;
  auto alloc = [&](size_t bytes) -> void* {
    void* p = ws + off;
    off += (bytes + 255) & ~(size_t)255;
    return p;
  };
  unsigned short* h_buf   = (unsigned short*)alloc((size_t)kRows * kDim * 2);
  unsigned short* qkv     = (unsigned short*)alloc((size_t)kRows * kQKV * 2);
  unsigned short* vT      = (unsigned short*)alloc((size_t)kB * kH * kDh * kN * 2);
  unsigned short* attnout = (unsigned short*)alloc((size_t)kRows * kDim * 2);
  unsigned short* mid     = (unsigned short*)alloc((size_t)kRows * kMlp * 2);
  unsigned short* wqT     = (unsigned short*)alloc((size_t)kDim * kDim * 2);
  unsigned short* wkvT    = (unsigned short*)alloc((size_t)2 * kDim * kDim * 2);
  unsigned short* woT     = (unsigned short*)alloc((size_t)kDim * kDim * 2);
  unsigned short* w1T     = (unsigned short*)alloc((size_t)kMlp * kDim * 2);
  unsigned short* w2T     = (unsigned short*)alloc((size_t)kDim * kMlp * 2);

  size_t base = off;
  int IC = 1024;
  while (IC > 32 && base + (size_t)(kB * kH) * IC * kN * 4 + 1024 > ws_size) IC >>= 1;
  unsigned short* dots = (unsigned short*)alloc((size_t)(kB * kH) * IC * kN * 2);
  unsigned short* pbuf = (unsigned short*)alloc((size_t)(kB * kH) * IC * kN * 2);

  hipMemcpyAsync(xo, x, (size_t)kRows * kDim * 4, hipMemcpyDeviceToDevice, stream);

  for (int L = 0; L < kDepth; ++L) {
    // --- attention block ---
    ln_kernel<<<kRows, 256, 0, stream>>>(xo, ln1_g + L * kDim, ln1_b + L * kDim, h_buf);
    transpose_w<<<dim3(kDim / 32, kDim / 32), 256, 0, stream>>>(
        Wq + (size_t)L * kDim * kDim, wqT, kDim, kDim);
    transpose_w<<<dim3(2 * kDim / 32, kDim / 32), 256, 0, stream>>>(
        Wkv + (size_t)L * kDim * 2 * kDim, wkvT, kDim, 2 * kDim);
    transpose_w<<<dim3(kDim / 32, kDim / 32), 256, 0, stream>>>(
        Wo + (size_t)L * kDim * kDim, woT, kDim, kDim);
    transpose_w<<<dim3(kMlp / 32, kDim / 32), 256, 0, stream>>>(
        W1 + (size_t)L * kDim * kMlp, w1T, kDim, kMlp);
    transpose_w<<<dim3(kDim / 32, kMlp / 32), 256, 0, stream>>>(
        W2 + (size_t)L * kMlp * kDim, w2T, kMlp, kDim);

    gemm_kernel<0><<<dim3(kDim / 128, kRows / 128), 256, 0, stream>>>(
        h_buf, wqT, nullptr, nullptr, nullptr, qkv, kDim, kQKV);
    gemm_kernel<0><<<dim3(2 * kDim / 128, kRows / 128), 256, 0, stream>>>(
        h_buf, wkvT, nullptr, nullptr, nullptr, qkv + kDim, kDim, kQKV);
    transpose_v_kernel<<<dim3(kN / 32, kDh / 32, kB * kH), 256, 0, stream>>>(qkv, vT);

    for (int i0 = 0; i0 < kN; i0 += IC) {
      dots_kernel<<<dim3(kN / 32, IC / 32, kB), 256, 0, stream>>>(
          qkv, pre + L * 144, dots, i0, IC);
      softmax_mix_kernel<<<dim3(IC, kB), 256, 0, stream>>>(
          dots, post + L * 144, pbuf, IC);
      pv_kernel<<<dim3(IC / 16, kH, kB), 256, 0, stream>>>(pbuf, vT, attnout, i0, IC);
    }
    gemm_kernel<2><<<dim3(kDim / 128, kRows / 128), 256, 0, stream>>>(
        attnout, woT, bo + L * kDim, s1 + L * kDim, xo, nullptr, kDim, kDim);

    // --- MLP block ---
    ln_kernel<<<kRows, 256, 0, stream>>>(xo, ln2_g + L * kDim, ln2_b + L * kDim, h_buf);
    gemm_kernel<1><<<dim3(kMlp / 128, kRows / 128), 256, 0, stream>>>(
        h_buf, w1T, b1 + L * kMlp, nullptr, nullptr, mid, kDim, kMlp);
    gemm_kernel<2><<<dim3(kDim / 128, kRows / 128), 256, 0, stream>>>(
        mid, w2T, b2 + L * kDim, s2 + L * kDim, xo, nullptr, kMlp, kDim);
  }
}

// Round 5
// 5133.332 us; speedup vs baseline: 1.4166x; 1.2174x over previous
//
#include <hip/hip_runtime.h>

constexpr int kDepth = 6;
constexpr int kB = 8;
constexpr int kN = 1024;
constexpr int kDim = 768;
constexpr int kH = 12;
constexpr int kDh = 64;
constexpr int kMlp = 3072;
constexpr int kRows = kB * kN;   // 8192
constexpr int kQKV = 2304;       // q(768) k(768) v(768)

typedef __attribute__((ext_vector_type(4))) float f32x4;
typedef __attribute__((ext_vector_type(8))) short bf16x8;

__device__ __forceinline__ f32x4 mfma16x16x32(bf16x8 a, bf16x8 b, f32x4 c) {
  return __builtin_amdgcn_mfma_f32_16x16x32_bf16(a, b, c, 0, 0, 0);
}

__device__ __forceinline__ unsigned short f2bf(float f) {
  unsigned int u = __builtin_bit_cast(unsigned int, f);
  u = u + 0x7FFFu + ((u >> 16) & 1u);
  return (unsigned short)(u >> 16);
}

__device__ __forceinline__ float bf2f(unsigned short u) {
  return __builtin_bit_cast(float, (unsigned int)u << 16);
}

__device__ __forceinline__ void gload_lds16(const void* g, void* l) {
  __builtin_amdgcn_global_load_lds((__attribute__((address_space(1))) void*)g,
                                   (__attribute__((address_space(3))) void*)l,
                                   16, 0, 0);
}

// ---------------- LayerNorm: f32 in -> bf16 out ----------------
__global__ __launch_bounds__(256) void ln_kernel(const float* __restrict__ x,
                                                 const float* __restrict__ gamma,
                                                 const float* __restrict__ beta,
                                                 unsigned short* __restrict__ out) {
  int row = blockIdx.x, tid = threadIdx.x;
  const float* xr = x + (size_t)row * kDim;
  float v0 = xr[tid], v1 = xr[tid + 256], v2 = xr[tid + 512];
  float s = v0 + v1 + v2;
  float q = v0 * v0 + v1 * v1 + v2 * v2;
#pragma unroll
  for (int o = 32; o >= 1; o >>= 1) {
    s += __shfl_xor(s, o);
    q += __shfl_xor(q, o);
  }
  __shared__ float ss[4], sq[4];
  int wid = tid >> 6, lane = tid & 63;
  if (lane == 0) { ss[wid] = s; sq[wid] = q; }
  __syncthreads();
  s = ss[0] + ss[1] + ss[2] + ss[3];
  q = sq[0] + sq[1] + sq[2] + sq[3];
  float mean = s * (1.0f / kDim);
  float var = q * (1.0f / kDim) - mean * mean;
  float rstd = rsqrtf(var + 1e-5f);
  unsigned short* orow = out + (size_t)row * kDim;
  orow[tid]       = f2bf((v0 - mean) * rstd * gamma[tid]       + beta[tid]);
  orow[tid + 256] = f2bf((v1 - mean) * rstd * gamma[tid + 256] + beta[tid + 256]);
  orow[tid + 512] = f2bf((v2 - mean) * rstd * gamma[tid + 512] + beta[tid + 512]);
}

// ---------------- Batched weight transpose: all 5 matrices of one layer ----------------
// f32 [R,C] -> bf16 [C+off, R]; 6912 tiles of 32x32
__global__ __launch_bounds__(256) void transpose_all(const float* __restrict__ Wq,
                                                     const float* __restrict__ Wkv,
                                                     const float* __restrict__ Wo,
                                                     const float* __restrict__ W1,
                                                     const float* __restrict__ W2,
                                                     unsigned short* __restrict__ wqkvT,
                                                     unsigned short* __restrict__ woT,
                                                     unsigned short* __restrict__ w1T,
                                                     unsigned short* __restrict__ w2T,
                                                     int L) {
  int t = blockIdx.x;
  const float* src;
  unsigned short* dst;
  int R, C, dstOff;
  if (t < 576)       { src = Wq  + (size_t)L * 768 * 768;  R = 768;  C = 768;  dst = wqkvT; dstOff = 0;   }
  else if (t < 1728) { src = Wkv + (size_t)L * 768 * 1536; R = 768;  C = 1536; dst = wqkvT; dstOff = 768; t -= 576; }
  else if (t < 2304) { src = Wo  + (size_t)L * 768 * 768;  R = 768;  C = 768;  dst = woT;   dstOff = 0;   t -= 1728; }
  else if (t < 4608) { src = W1  + (size_t)L * 768 * 3072; R = 768;  C = 3072; dst = w1T;   dstOff = 0;   t -= 2304; }
  else               { src = W2  + (size_t)L * 3072 * 768; R = 3072; C = 768;  dst = w2T;   dstOff = 0;   t -= 4608; }
  int Ct = C >> 5;
  int bx = t % Ct, by = t / Ct;
  __shared__ float tt[32][33];
  int tx = threadIdx.x & 31, ty = threadIdx.x >> 5;  // ty 0..7
  int c0 = bx * 32, r0 = by * 32;
#pragma unroll
  for (int k = 0; k < 4; ++k) {
    int r = r0 + ty + k * 8;
    tt[ty + k * 8][tx] = src[(size_t)r * C + c0 + tx];
  }
  __syncthreads();
#pragma unroll
  for (int k = 0; k < 4; ++k) {
    int c = c0 + ty + k * 8;
    dst[(size_t)(dstOff + c) * R + r0 + tx] = f2bf(tt[tx][ty + k * 8]);
  }
}

// ---------------- V transpose: qkv[b,j,1536+g*64+d] -> vT[(b*12+g)*64+d][j] ----------------
__global__ __launch_bounds__(256) void transpose_v_kernel(const unsigned short* __restrict__ qkv,
                                                          unsigned short* __restrict__ vT) {
  __shared__ unsigned short t[32][33];
  int tx = threadIdx.x & 31, ty = threadIdx.x >> 5;
  int j0 = blockIdx.x * 32, d0 = blockIdx.y * 32;
  int bg = blockIdx.z;
  int b = bg / kH, g = bg % kH;
#pragma unroll
  for (int k = 0; k < 4; ++k) {
    int j = j0 + ty + k * 8;
    t[ty + k * 8][tx] = qkv[(size_t)(b * kN + j) * kQKV + 1536 + g * 64 + d0 + tx];
  }
  __syncthreads();
#pragma unroll
  for (int k = 0; k < 4; ++k) {
    int d = d0 + ty + k * 8;
    vT[((size_t)(b * kH + g) * kDh + d) * kN + j0 + tx] = t[tx][ty + k * 8];
  }
}

// ---------------- GEMM: A[M,K]bf16 x Bt[N,K]bf16 -> epilogue ----------------
// EPI 0: C=bf16 plain; EPI 1: bf16 gelu(acc+bias); EPI 2: resid = (acc+bias)*scl + resid (f32)
template <int EPI>
__global__ __launch_bounds__(256) void gemm_kernel(const unsigned short* __restrict__ A,
                                                   const unsigned short* __restrict__ Bt,
                                                   const float* __restrict__ bias,
                                                   const float* __restrict__ scl,
                                                   float* __restrict__ resid,
                                                   unsigned short* __restrict__ C,
                                                   int K, int ldc) {
  __shared__ __align__(16) unsigned short lA[128 * 64];
  __shared__ __align__(16) unsigned short lB[128 * 64];
  int tid = threadIdx.x, wid = tid >> 6, lane = tid & 63;
  // XCD-aware bijective chunked swizzle (all grids have nwg % 8 == 0)
  int gx = gridDim.x;
  int nwg = gx * gridDim.y;
  int orig = blockIdx.y * gx + blockIdx.x;
  int chunk = nwg >> 3;
  int wg = (orig & 7) * chunk + (orig >> 3);
  int bx = wg % gx, by = wg / gx;
  int row0 = by * 128, col0 = bx * 128;
  int wr = wid >> 1, wc = wid & 1;
  f32x4 zero = {0.f, 0.f, 0.f, 0.f};
  f32x4 acc[4][4];
#pragma unroll
  for (int m = 0; m < 4; ++m)
#pragma unroll
    for (int n = 0; n < 4; ++n) acc[m][n] = zero;

  for (int kt = 0; kt < K; kt += 64) {
    __syncthreads();
#pragma unroll
    for (int t = 0; t < 4; ++t) {
      int cbase = wid * 256 + t * 64;
      int c = cbase + lane;
      int r = c >> 3, slot = c & 7;
      int k8 = slot ^ (r & 7);  // source-swizzle so LDS holds XOR-swizzled layout
      gload_lds16(&A[(size_t)(row0 + r) * K + kt + k8 * 8], &lA[cbase * 8]);
      gload_lds16(&Bt[(size_t)(col0 + r) * K + kt + k8 * 8], &lB[cbase * 8]);
    }
    __syncthreads();
#pragma unroll
    for (int kk = 0; kk < 2; ++kk) {
      bf16x8 af[4], bfr[4];
      int kslot = kk * 4 + (lane >> 4);
#pragma unroll
      for (int m = 0; m < 4; ++m) {
        int r = wr * 64 + m * 16 + (lane & 15);
        af[m] = *reinterpret_cast<const bf16x8*>(&lA[r * 64 + ((kslot ^ (r & 7)) << 3)]);
      }
#pragma unroll
      for (int n = 0; n < 4; ++n) {
        int r = wc * 64 + n * 16 + (lane & 15);
        bfr[n] = *reinterpret_cast<const bf16x8*>(&lB[r * 64 + ((kslot ^ (r & 7)) << 3)]);
      }
#pragma unroll
      for (int m = 0; m < 4; ++m)
#pragma unroll
        for (int n = 0; n < 4; ++n) acc[m][n] = mfma16x16x32(af[m], bfr[n], acc[m][n]);
    }
  }
#pragma unroll
  for (int m = 0; m < 4; ++m)
#pragma unroll
    for (int n = 0; n < 4; ++n)
#pragma unroll
      for (int r4 = 0; r4 < 4; ++r4) {
        int row = row0 + wr * 64 + m * 16 + ((lane >> 4) << 2) + r4;
        int col = col0 + wc * 64 + n * 16 + (lane & 15);
        float v = acc[m][n][r4];
        if (EPI == 0) {
          C[(size_t)row * ldc + col] = f2bf(v);
        } else if (EPI == 1) {
          v += bias[col];
          v = 0.5f * v * (1.f + erff(v * 0.70710678118654752f));
          C[(size_t)row * ldc + col] = f2bf(v);
        } else {
          v = (v + bias[col]) * scl[col];
          size_t idx = (size_t)row * kDim + col;
          resid[idx] = resid[idx] + v;
        }
      }
}

// ---------------- QK^T raw per-head scores -> dots bf16 (no mix, no scale) ----------------
__global__ __launch_bounds__(256) void dots_kernel(const unsigned short* __restrict__ qkv,
                                                   unsigned short* __restrict__ dots,
                                                   int i0, int IC) {
  int tid = threadIdx.x, wid = tid >> 6, lane = tid & 63;
  int kg = lane >> 4, l15 = lane & 15;
  int j0 = blockIdx.x * 32;
  int il0 = blockIdx.y * 32;
  int b = blockIdx.z;
  f32x4 zero = {0.f, 0.f, 0.f, 0.f};
#pragma unroll
  for (int rep = 0; rep < 3; ++rep) {
    int h = rep * 4 + wid;
    f32x4 acc[2][2];
    acc[0][0] = zero; acc[0][1] = zero; acc[1][0] = zero; acc[1][1] = zero;
#pragma unroll
    for (int kk = 0; kk < 2; ++kk) {
      bf16x8 aq[2], bk[2];
#pragma unroll
      for (int m = 0; m < 2; ++m) {
        int tok = i0 + il0 + m * 16 + l15;
        aq[m] = *reinterpret_cast<const bf16x8*>(
            &qkv[(size_t)(b * kN + tok) * kQKV + h * 64 + kk * 32 + kg * 8]);
      }
#pragma unroll
      for (int n = 0; n < 2; ++n) {
        int tj = j0 + n * 16 + l15;
        bk[n] = *reinterpret_cast<const bf16x8*>(
            &qkv[(size_t)(b * kN + tj) * kQKV + 768 + h * 64 + kk * 32 + kg * 8]);
      }
#pragma unroll
      for (int m = 0; m < 2; ++m)
#pragma unroll
        for (int n = 0; n < 2; ++n) acc[m][n] = mfma16x16x32(aq[m], bk[n], acc[m][n]);
    }
#pragma unroll
    for (int m = 0; m < 2; ++m)
#pragma unroll
      for (int n = 0; n < 2; ++n)
#pragma unroll
        for (int r = 0; r < 4; ++r)
          dots[((size_t)(b * kH + h) * IC + il0 + m * 16 + kg * 4 + r) * kN +
               j0 + n * 16 + l15] = f2bf(acc[m][n][r]);
  }
}

// ---------------- premix (scale folded) + softmax (no-max+clamp) + postmix -> p bf16 ----------------
__global__ __launch_bounds__(256) void softmax_mix_kernel(const unsigned short* __restrict__ dots,
                                                          const float* __restrict__ pre,
                                                          const float* __restrict__ post,
                                                          unsigned short* __restrict__ pbuf,
                                                          int IC) {
  __shared__ unsigned short raw[kH][kN];
  __shared__ unsigned short mixed[kH][kN];
  __shared__ float lg[kH];
  __shared__ float spre[144], spost[144];
  int tid = threadIdx.x, wid = tid >> 6, lane = tid & 63;
  int i = blockIdx.x, b = blockIdx.y;
  if (tid < 144) { spre[tid] = pre[tid] * 0.125f; spost[tid] = post[tid]; }
  for (int h = 0; h < kH; ++h)
    for (int j = tid; j < kN; j += 256)
      raw[h][j] = dots[((size_t)(b * kH + h) * IC + i) * kN + j];
  __syncthreads();
  // pass A: mixed scores + denominators (4 waves x 3 g)
  for (int rep = 0; rep < 3; ++rep) {
    int g = rep * 4 + wid;
    float sum = 0.f;
    for (int j = lane; j < kN; j += 64) {
      float m = 0.f;
#pragma unroll
      for (int h = 0; h < kH; ++h) m += bf2f(raw[h][j]) * spre[h * 12 + g];
      m = fminf(fmaxf(m, -15.f), 15.f);
      unsigned short mb = f2bf(m);
      mixed[g][j] = mb;
      sum += __expf(bf2f(mb));
    }
#pragma unroll
    for (int o = 32; o >= 1; o >>= 1) sum += __shfl_xor(sum, o);
    if (lane == 0) lg[g] = 1.f / sum;
  }
  __syncthreads();
  // pass B: normalize + postmix
  for (int j = tid; j < kN; j += 256) {
    float a[kH];
#pragma unroll
    for (int h = 0; h < kH; ++h) a[h] = __expf(bf2f(mixed[h][j])) * lg[h];
#pragma unroll
    for (int g2 = 0; g2 < kH; ++g2) {
      float o = 0.f;
#pragma unroll
      for (int h = 0; h < kH; ++h) o += a[h] * spost[h * 12 + g2];
      pbuf[((size_t)(b * kH + g2) * IC + i) * kN + j] = f2bf(o);
    }
  }
}

// ---------------- PV: out[b,i,g*64+d] = sum_j p[b,g,i,j] * v[b,g,j,d] (32 i-rows/block) --------
__global__ __launch_bounds__(256) void pv_kernel(const unsigned short* __restrict__ pbuf,
                                                 const unsigned short* __restrict__ vT,
                                                 unsigned short* __restrict__ attn_out,
                                                 int i0, int IC) {
  int tid = threadIdx.x, wid = tid >> 6, lane = tid & 63;
  int kg = lane >> 4, l15 = lane & 15;
  int i32 = blockIdx.x * 32;
  int g = blockIdx.y, b = blockIdx.z;
  const unsigned short* prow = pbuf + (size_t)(b * kH + g) * IC * kN;
  const unsigned short* vrow = vT + (size_t)(b * kH + g) * kDh * kN;
  f32x4 zero = {0.f, 0.f, 0.f, 0.f};
  f32x4 acc[2][4];
#pragma unroll
  for (int half = 0; half < 2; ++half)
#pragma unroll
    for (int n = 0; n < 4; ++n) acc[half][n] = zero;
#pragma unroll
  for (int s = 0; s < 8; ++s) {
    int kt = (wid * 8 + s) * 32 + kg * 8;
    bf16x8 ap[2];
#pragma unroll
    for (int half = 0; half < 2; ++half)
      ap[half] = *reinterpret_cast<const bf16x8*>(&prow[(size_t)(i32 + half * 16 + l15) * kN + kt]);
#pragma unroll
    for (int n = 0; n < 4; ++n) {
      bf16x8 bv = *reinterpret_cast<const bf16x8*>(&vrow[(size_t)(n * 16 + l15) * kN + kt]);
#pragma unroll
      for (int half = 0; half < 2; ++half)
        acc[half][n] = mfma16x16x32(ap[half], bv, acc[half][n]);
    }
  }
  __shared__ float red[3][32][64];
  if (wid > 0) {
#pragma unroll
    for (int half = 0; half < 2; ++half)
#pragma unroll
      for (int n = 0; n < 4; ++n)
#pragma unroll
        for (int r = 0; r < 4; ++r)
          red[wid - 1][half * 16 + kg * 4 + r][n * 16 + l15] = acc[half][n][r];
  }
  __syncthreads();
  if (wid == 0) {
#pragma unroll
    for (int half = 0; half < 2; ++half)
#pragma unroll
      for (int n = 0; n < 4; ++n)
#pragma unroll
        for (int r = 0; r < 4; ++r) {
          int rr = half * 16 + kg * 4 + r, cc = n * 16 + l15;
          float v = acc[half][n][r] + red[0][rr][cc] + red[1][rr][cc] + red[2][rr][cc];
          int tok = i0 + i32 + rr;
          attn_out[(size_t)(b * kN + tok) * kDim + g * kDh + cc] = f2bf(v);
        }
  }
}

extern "C" void kernel_launch(void* const* d_in, const int* in_sizes, int n_in,
                              void* d_out, int out_size, void* d_ws, size_t ws_size,
                              hipStream_t stream) {
  (void)in_sizes; (void)n_in; (void)out_size;
  const float* x     = (const float*)d_in[0];
  const float* ln1_g = (const float*)d_in[1];
  const float* ln1_b = (const float*)d_in[2];
  const float* Wq    = (const float*)d_in[3];
  const float* Wkv   = (const float*)d_in[4];
  const float* pre   = (const float*)d_in[5];
  const float* post  = (const float*)d_in[6];
  const float* Wo    = (const float*)d_in[7];
  const float* bo    = (const float*)d_in[8];
  const float* s1    = (const float*)d_in[9];
  const float* ln2_g = (const float*)d_in[10];
  const float* ln2_b = (const float*)d_in[11];
  const float* W1    = (const float*)d_in[12];
  const float* b1    = (const float*)d_in[13];
  const float* W2    = (const float*)d_in[14];
  const float* b2    = (const float*)d_in[15];
  const float* s2    = (const float*)d_in[16];
  float* xo = (float*)d_out;

  char* ws = (char*)d_ws;
  size_t off = 0;
  auto alloc = [&](size_t bytes) -> void* {
    void* p = ws + off;
    off += (bytes + 255) & ~(size_t)255;
    return p;
  };
  unsigned short* h_buf   = (unsigned short*)alloc((size_t)kRows * kDim * 2);
  unsigned short* qkv     = (unsigned short*)alloc((size_t)kRows * kQKV * 2);
  unsigned short* vT      = (unsigned short*)alloc((size_t)kB * kH * kDh * kN * 2);
  unsigned short* attnout = (unsigned short*)alloc((size_t)kRows * kDim * 2);
  unsigned short* mid     = (unsigned short*)alloc((size_t)kRows * kMlp * 2);
  unsigned short* wqkvT   = (unsigned short*)alloc((size_t)kQKV * kDim * 2);
  unsigned short* woT     = (unsigned short*)alloc((size_t)kDim * kDim * 2);
  unsigned short* w1T     = (unsigned short*)alloc((size_t)kMlp * kDim * 2);
  unsigned short* w2T     = (unsigned short*)alloc((size_t)kDim * kMlp * 2);

  size_t base = off;
  int IC = 1024;
  while (IC > 32 && base + (size_t)(kB * kH) * IC * kN * 4 + 1024 > ws_size) IC >>= 1;
  unsigned short* dots = (unsigned short*)alloc((size_t)(kB * kH) * IC * kN * 2);
  unsigned short* pbuf = (unsigned short*)alloc((size_t)(kB * kH) * IC * kN * 2);

  hipMemcpyAsync(xo, x, (size_t)kRows * kDim * 4, hipMemcpyDeviceToDevice, stream);

  for (int L = 0; L < kDepth; ++L) {
    // --- attention block ---
    ln_kernel<<<kRows, 256, 0, stream>>>(xo, ln1_g + L * kDim, ln1_b + L * kDim, h_buf);
    transpose_all<<<6912, 256, 0, stream>>>(Wq, Wkv, Wo, W1, W2, wqkvT, woT, w1T, w2T, L);

    gemm_kernel<0><<<dim3(kQKV / 128, kRows / 128), 256, 0, stream>>>(
        h_buf, wqkvT, nullptr, nullptr, nullptr, qkv, kDim, kQKV);
    transpose_v_kernel<<<dim3(kN / 32, kDh / 32, kB * kH), 256, 0, stream>>>(qkv, vT);

    for (int i0 = 0; i0 < kN; i0 += IC) {
      dots_kernel<<<dim3(kN / 32, IC / 32, kB), 256, 0, stream>>>(qkv, dots, i0, IC);
      softmax_mix_kernel<<<dim3(IC, kB), 256, 0, stream>>>(
          dots, pre + L * 144, post + L * 144, pbuf, IC);
      pv_kernel<<<dim3(IC / 32, kH, kB), 256, 0, stream>>>(pbuf, vT, attnout, i0, IC);
    }
    gemm_kernel<2><<<dim3(kDim / 128, kRows / 128), 256, 0, stream>>>(
        attnout, woT, bo + L * kDim, s1 + L * kDim, xo, nullptr, kDim, kDim);

    // --- MLP block ---
    ln_kernel<<<kRows, 256, 0, stream>>>(xo, ln2_g + L * kDim, ln2_b + L * kDim, h_buf);
    gemm_kernel<1><<<dim3(kMlp / 128, kRows / 128), 256, 0, stream>>>(
        h_buf, w1T, b1 + L * kMlp, nullptr, nullptr, mid, kDim, kMlp);
    gemm_kernel<2><<<dim3(kDim / 128, kRows / 128), 256, 0, stream>>>(
        mid, w2T, b2 + L * kDim, s2 + L * kDim, xo, nullptr, kMlp, kDim);
  }
}

// Round 6
// 4337.702 us; speedup vs baseline: 1.6765x; 1.1834x over previous
//
#include <hip/hip_runtime.h>

constexpr int kDepth = 6;
constexpr int kB = 8;
constexpr int kN = 1024;
constexpr int kDim = 768;
constexpr int kH = 12;
constexpr int kDh = 64;
constexpr int kMlp = 3072;
constexpr int kRows = kB * kN;   // 8192
constexpr int kQKV = 2304;       // q(768) k(768) v(768)

typedef __attribute__((ext_vector_type(4))) float f32x4;
typedef __attribute__((ext_vector_type(8))) short bf16x8;

__device__ __forceinline__ f32x4 mfma16x16x32(bf16x8 a, bf16x8 b, f32x4 c) {
  return __builtin_amdgcn_mfma_f32_16x16x32_bf16(a, b, c, 0, 0, 0);
}

__device__ __forceinline__ unsigned short f2bf(float f) {
  unsigned int u = __builtin_bit_cast(unsigned int, f);
  u = u + 0x7FFFu + ((u >> 16) & 1u);
  return (unsigned short)(u >> 16);
}

__device__ __forceinline__ float bf2f(unsigned short u) {
  return __builtin_bit_cast(float, (unsigned int)u << 16);
}

__device__ __forceinline__ void gload_lds16(const void* g, void* l) {
  __builtin_amdgcn_global_load_lds((__attribute__((address_space(1))) void*)g,
                                   (__attribute__((address_space(3))) void*)l,
                                   16, 0, 0);
}

// ---------------- LayerNorm: f32 in -> bf16 out ----------------
__global__ __launch_bounds__(256) void ln_kernel(const float* __restrict__ x,
                                                 const float* __restrict__ gamma,
                                                 const float* __restrict__ beta,
                                                 unsigned short* __restrict__ out) {
  int row = blockIdx.x, tid = threadIdx.x;
  const float* xr = x + (size_t)row * kDim;
  float v0 = xr[tid], v1 = xr[tid + 256], v2 = xr[tid + 512];
  float s = v0 + v1 + v2;
  float q = v0 * v0 + v1 * v1 + v2 * v2;
#pragma unroll
  for (int o = 32; o >= 1; o >>= 1) {
    s += __shfl_xor(s, o);
    q += __shfl_xor(q, o);
  }
  __shared__ float ss[4], sq[4];
  int wid = tid >> 6, lane = tid & 63;
  if (lane == 0) { ss[wid] = s; sq[wid] = q; }
  __syncthreads();
  s = ss[0] + ss[1] + ss[2] + ss[3];
  q = sq[0] + sq[1] + sq[2] + sq[3];
  float mean = s * (1.0f / kDim);
  float var = q * (1.0f / kDim) - mean * mean;
  float rstd = rsqrtf(var + 1e-5f);
  unsigned short* orow = out + (size_t)row * kDim;
  orow[tid]       = f2bf((v0 - mean) * rstd * gamma[tid]       + beta[tid]);
  orow[tid + 256] = f2bf((v1 - mean) * rstd * gamma[tid + 256] + beta[tid + 256]);
  orow[tid + 512] = f2bf((v2 - mean) * rstd * gamma[tid + 512] + beta[tid + 512]);
}

// ---------------- Batched weight transpose: all 5 matrices of one layer ----------------
// f32 [R,C] -> bf16 [C+off, R]; 6912 tiles of 32x32
__global__ __launch_bounds__(256) void transpose_all(const float* __restrict__ Wq,
                                                     const float* __restrict__ Wkv,
                                                     const float* __restrict__ Wo,
                                                     const float* __restrict__ W1,
                                                     const float* __restrict__ W2,
                                                     unsigned short* __restrict__ wqkvT,
                                                     unsigned short* __restrict__ woT,
                                                     unsigned short* __restrict__ w1T,
                                                     unsigned short* __restrict__ w2T,
                                                     int L) {
  int t = blockIdx.x;
  const float* src;
  unsigned short* dst;
  int R, C, dstOff;
  if (t < 576)       { src = Wq  + (size_t)L * 768 * 768;  R = 768;  C = 768;  dst = wqkvT; dstOff = 0;   }
  else if (t < 1728) { src = Wkv + (size_t)L * 768 * 1536; R = 768;  C = 1536; dst = wqkvT; dstOff = 768; t -= 576; }
  else if (t < 2304) { src = Wo  + (size_t)L * 768 * 768;  R = 768;  C = 768;  dst = woT;   dstOff = 0;   t -= 1728; }
  else if (t < 4608) { src = W1  + (size_t)L * 768 * 3072; R = 768;  C = 3072; dst = w1T;   dstOff = 0;   t -= 2304; }
  else               { src = W2  + (size_t)L * 3072 * 768; R = 3072; C = 768;  dst = w2T;   dstOff = 0;   t -= 4608; }
  int Ct = C >> 5;
  int bx = t % Ct, by = t / Ct;
  __shared__ float tt[32][33];
  int tx = threadIdx.x & 31, ty = threadIdx.x >> 5;  // ty 0..7
  int c0 = bx * 32, r0 = by * 32;
#pragma unroll
  for (int k = 0; k < 4; ++k) {
    int r = r0 + ty + k * 8;
    tt[ty + k * 8][tx] = src[(size_t)r * C + c0 + tx];
  }
  __syncthreads();
#pragma unroll
  for (int k = 0; k < 4; ++k) {
    int c = c0 + ty + k * 8;
    dst[(size_t)(dstOff + c) * R + r0 + tx] = f2bf(tt[tx][ty + k * 8]);
  }
}

// ---------------- V transpose: qkv[b,j,1536+g*64+d] -> vT[(b*12+g)*64+d][j] ----------------
__global__ __launch_bounds__(256) void transpose_v_kernel(const unsigned short* __restrict__ qkv,
                                                          unsigned short* __restrict__ vT) {
  __shared__ unsigned short t[32][33];
  int tx = threadIdx.x & 31, ty = threadIdx.x >> 5;
  int j0 = blockIdx.x * 32, d0 = blockIdx.y * 32;
  int bg = blockIdx.z;
  int b = bg / kH, g = bg % kH;
#pragma unroll
  for (int k = 0; k < 4; ++k) {
    int j = j0 + ty + k * 8;
    t[ty + k * 8][tx] = qkv[(size_t)(b * kN + j) * kQKV + 1536 + g * 64 + d0 + tx];
  }
  __syncthreads();
#pragma unroll
  for (int k = 0; k < 4; ++k) {
    int d = d0 + ty + k * 8;
    vT[((size_t)(b * kH + g) * kDh + d) * kN + j0 + tx] = t[tx][ty + k * 8];
  }
}

// ---------------- GEMM: A[M,K]bf16 x Bt[N,K]bf16 -> epilogue ----------------
// EPI 0: C=bf16 plain; EPI 1: bf16 gelu(acc+bias); EPI 2: resid = (acc+bias)*scl + resid (f32)
template <int EPI>
__global__ __launch_bounds__(256) void gemm_kernel(const unsigned short* __restrict__ A,
                                                   const unsigned short* __restrict__ Bt,
                                                   const float* __restrict__ bias,
                                                   const float* __restrict__ scl,
                                                   float* __restrict__ resid,
                                                   unsigned short* __restrict__ C,
                                                   int K, int ldc) {
  __shared__ __align__(16) unsigned short lA[128 * 64];
  __shared__ __align__(16) unsigned short lB[128 * 64];
  int tid = threadIdx.x, wid = tid >> 6, lane = tid & 63;
  // XCD-aware bijective chunked swizzle (all grids have nwg % 8 == 0)
  int gx = gridDim.x;
  int nwg = gx * gridDim.y;
  int orig = blockIdx.y * gx + blockIdx.x;
  int chunk = nwg >> 3;
  int wg = (orig & 7) * chunk + (orig >> 3);
  int bx = wg % gx, by = wg / gx;
  int row0 = by * 128, col0 = bx * 128;
  int wr = wid >> 1, wc = wid & 1;
  f32x4 zero = {0.f, 0.f, 0.f, 0.f};
  f32x4 acc[4][4];
#pragma unroll
  for (int m = 0; m < 4; ++m)
#pragma unroll
    for (int n = 0; n < 4; ++n) acc[m][n] = zero;

  for (int kt = 0; kt < K; kt += 64) {
    __syncthreads();
#pragma unroll
    for (int t = 0; t < 4; ++t) {
      int cbase = wid * 256 + t * 64;
      int c = cbase + lane;
      int r = c >> 3, slot = c & 7;
      int k8 = slot ^ (r & 7);  // source-swizzle so LDS holds XOR-swizzled layout
      gload_lds16(&A[(size_t)(row0 + r) * K + kt + k8 * 8], &lA[cbase * 8]);
      gload_lds16(&Bt[(size_t)(col0 + r) * K + kt + k8 * 8], &lB[cbase * 8]);
    }
    __syncthreads();
#pragma unroll
    for (int kk = 0; kk < 2; ++kk) {
      bf16x8 af[4], bfr[4];
      int kslot = kk * 4 + (lane >> 4);
#pragma unroll
      for (int m = 0; m < 4; ++m) {
        int r = wr * 64 + m * 16 + (lane & 15);
        af[m] = *reinterpret_cast<const bf16x8*>(&lA[r * 64 + ((kslot ^ (r & 7)) << 3)]);
      }
#pragma unroll
      for (int n = 0; n < 4; ++n) {
        int r = wc * 64 + n * 16 + (lane & 15);
        bfr[n] = *reinterpret_cast<const bf16x8*>(&lB[r * 64 + ((kslot ^ (r & 7)) << 3)]);
      }
#pragma unroll
      for (int m = 0; m < 4; ++m)
#pragma unroll
        for (int n = 0; n < 4; ++n) acc[m][n] = mfma16x16x32(af[m], bfr[n], acc[m][n]);
    }
  }
#pragma unroll
  for (int m = 0; m < 4; ++m)
#pragma unroll
    for (int n = 0; n < 4; ++n)
#pragma unroll
      for (int r4 = 0; r4 < 4; ++r4) {
        int row = row0 + wr * 64 + m * 16 + ((lane >> 4) << 2) + r4;
        int col = col0 + wc * 64 + n * 16 + (lane & 15);
        float v = acc[m][n][r4];
        if (EPI == 0) {
          C[(size_t)row * ldc + col] = f2bf(v);
        } else if (EPI == 1) {
          v += bias[col];
          v = 0.5f * v * (1.f + erff(v * 0.70710678118654752f));
          C[(size_t)row * ldc + col] = f2bf(v);
        } else {
          v = (v + bias[col]) * scl[col];
          size_t idx = (size_t)row * kDim + col;
          resid[idx] = resid[idx] + v;
        }
      }
}

// ---------------- QK^T raw per-head scores -> dots bf16 (no mix, no scale) ----------------
__global__ __launch_bounds__(256) void dots_kernel(const unsigned short* __restrict__ qkv,
                                                   unsigned short* __restrict__ dots,
                                                   int i0, int IC) {
  int tid = threadIdx.x, wid = tid >> 6, lane = tid & 63;
  int kg = lane >> 4, l15 = lane & 15;
  int j0 = blockIdx.x * 32;
  int il0 = blockIdx.y * 32;
  int b = blockIdx.z;
  f32x4 zero = {0.f, 0.f, 0.f, 0.f};
#pragma unroll
  for (int rep = 0; rep < 3; ++rep) {
    int h = rep * 4 + wid;
    f32x4 acc[2][2];
    acc[0][0] = zero; acc[0][1] = zero; acc[1][0] = zero; acc[1][1] = zero;
#pragma unroll
    for (int kk = 0; kk < 2; ++kk) {
      bf16x8 aq[2], bk[2];
#pragma unroll
      for (int m = 0; m < 2; ++m) {
        int tok = i0 + il0 + m * 16 + l15;
        aq[m] = *reinterpret_cast<const bf16x8*>(
            &qkv[(size_t)(b * kN + tok) * kQKV + h * 64 + kk * 32 + kg * 8]);
      }
#pragma unroll
      for (int n = 0; n < 2; ++n) {
        int tj = j0 + n * 16 + l15;
        bk[n] = *reinterpret_cast<const bf16x8*>(
            &qkv[(size_t)(b * kN + tj) * kQKV + 768 + h * 64 + kk * 32 + kg * 8]);
      }
#pragma unroll
      for (int m = 0; m < 2; ++m)
#pragma unroll
        for (int n = 0; n < 2; ++n) acc[m][n] = mfma16x16x32(aq[m], bk[n], acc[m][n]);
    }
#pragma unroll
    for (int m = 0; m < 2; ++m)
#pragma unroll
      for (int n = 0; n < 2; ++n)
#pragma unroll
        for (int r = 0; r < 4; ++r)
          dots[((size_t)(b * kH + h) * IC + il0 + m * 16 + kg * 4 + r) * kN +
               j0 + n * 16 + l15] = f2bf(acc[m][n][r]);
  }
}

// ---------------- premix (scale folded) + softmax (no-max+clamp) + postmix -> p bf16 ----------
// Register-resident: each thread owns 4 columns, no LDS staging of rows.
__global__ __launch_bounds__(256) void softmax_mix_kernel(const unsigned short* __restrict__ dots,
                                                          const float* __restrict__ pre,
                                                          const float* __restrict__ post,
                                                          unsigned short* __restrict__ pbuf,
                                                          int IC) {
  __shared__ float spre[144], spost[144];
  __shared__ float red[4][kH];
  __shared__ float lg[kH];
  int tid = threadIdx.x, wid = tid >> 6, lane = tid & 63;
  int i = blockIdx.x, b = blockIdx.y;
  if (tid < 144) { spre[tid] = pre[tid] * 0.125f; spost[tid] = post[tid]; }
  __syncthreads();

  const unsigned short* drow = dots + ((size_t)(b * kH) * IC + i) * kN;
  float e[4][kH];
  float psum[kH];
#pragma unroll
  for (int g = 0; g < kH; ++g) psum[g] = 0.f;

#pragma unroll
  for (int c = 0; c < 4; ++c) {
    int j = c * 256 + tid;
    float raw[kH];
#pragma unroll
    for (int h = 0; h < kH; ++h)
      raw[h] = bf2f(drow[(size_t)h * IC * kN + j]);
#pragma unroll
    for (int g = 0; g < kH; ++g) {
      float m = 0.f;
#pragma unroll
      for (int h = 0; h < kH; ++h) m += raw[h] * spre[h * 12 + g];
      m = fminf(fmaxf(m, -15.f), 15.f);
      float ee = __expf(m);
      e[c][g] = ee;
      psum[g] += ee;
    }
  }
  // reduce psum over the wave, then across 4 waves
#pragma unroll
  for (int g = 0; g < kH; ++g) {
#pragma unroll
    for (int o = 32; o >= 1; o >>= 1) psum[g] += __shfl_xor(psum[g], o);
  }
  if (lane == 0) {
#pragma unroll
    for (int g = 0; g < kH; ++g) red[wid][g] = psum[g];
  }
  __syncthreads();
  if (tid < kH) lg[tid] = 1.f / (red[0][tid] + red[1][tid] + red[2][tid] + red[3][tid]);
  __syncthreads();

  unsigned short* prow = pbuf + ((size_t)(b * kH) * IC + i) * kN;
#pragma unroll
  for (int c = 0; c < 4; ++c) {
    int j = c * 256 + tid;
    float a[kH];
#pragma unroll
    for (int h = 0; h < kH; ++h) a[h] = e[c][h] * lg[h];
#pragma unroll
    for (int g2 = 0; g2 < kH; ++g2) {
      float o = 0.f;
#pragma unroll
      for (int h = 0; h < kH; ++h) o += a[h] * spost[h * 12 + g2];
      prow[(size_t)g2 * IC * kN + j] = f2bf(o);
    }
  }
}

// ---------------- PV: out[b,i,g*64+d] = sum_j p[b,g,i,j] * v[b,g,j,d] (32 i-rows/block) --------
__global__ __launch_bounds__(256) void pv_kernel(const unsigned short* __restrict__ pbuf,
                                                 const unsigned short* __restrict__ vT,
                                                 unsigned short* __restrict__ attn_out,
                                                 int i0, int IC) {
  int tid = threadIdx.x, wid = tid >> 6, lane = tid & 63;
  int kg = lane >> 4, l15 = lane & 15;
  int i32 = blockIdx.x * 32;
  int g = blockIdx.y, b = blockIdx.z;
  const unsigned short* prow = pbuf + (size_t)(b * kH + g) * IC * kN;
  const unsigned short* vrow = vT + (size_t)(b * kH + g) * kDh * kN;
  f32x4 zero = {0.f, 0.f, 0.f, 0.f};
  f32x4 acc[2][4];
#pragma unroll
  for (int half = 0; half < 2; ++half)
#pragma unroll
    for (int n = 0; n < 4; ++n) acc[half][n] = zero;
#pragma unroll
  for (int s = 0; s < 8; ++s) {
    int kt = (wid * 8 + s) * 32 + kg * 8;
    bf16x8 ap[2];
#pragma unroll
    for (int half = 0; half < 2; ++half)
      ap[half] = *reinterpret_cast<const bf16x8*>(&prow[(size_t)(i32 + half * 16 + l15) * kN + kt]);
#pragma unroll
    for (int n = 0; n < 4; ++n) {
      bf16x8 bv = *reinterpret_cast<const bf16x8*>(&vrow[(size_t)(n * 16 + l15) * kN + kt]);
#pragma unroll
      for (int half = 0; half < 2; ++half)
        acc[half][n] = mfma16x16x32(ap[half], bv, acc[half][n]);
    }
  }
  __shared__ float red[3][32][64];
  if (wid > 0) {
#pragma unroll
    for (int half = 0; half < 2; ++half)
#pragma unroll
      for (int n = 0; n < 4; ++n)
#pragma unroll
        for (int r = 0; r < 4; ++r)
          red[wid - 1][half * 16 + kg * 4 + r][n * 16 + l15] = acc[half][n][r];
  }
  __syncthreads();
  if (wid == 0) {
#pragma unroll
    for (int half = 0; half < 2; ++half)
#pragma unroll
      for (int n = 0; n < 4; ++n)
#pragma unroll
        for (int r = 0; r < 4; ++r) {
          int rr = half * 16 + kg * 4 + r, cc = n * 16 + l15;
          float v = acc[half][n][r] + red[0][rr][cc] + red[1][rr][cc] + red[2][rr][cc];
          int tok = i0 + i32 + rr;
          attn_out[(size_t)(b * kN + tok) * kDim + g * kDh + cc] = f2bf(v);
        }
  }
}

extern "C" void kernel_launch(void* const* d_in, const int* in_sizes, int n_in,
                              void* d_out, int out_size, void* d_ws, size_t ws_size,
                              hipStream_t stream) {
  (void)in_sizes; (void)n_in; (void)out_size;
  const float* x     = (const float*)d_in[0];
  const float* ln1_g = (const float*)d_in[1];
  const float* ln1_b = (const float*)d_in[2];
  const float* Wq    = (const float*)d_in[3];
  const float* Wkv   = (const float*)d_in[4];
  const float* pre   = (const float*)d_in[5];
  const float* post  = (const float*)d_in[6];
  const float* Wo    = (const float*)d_in[7];
  const float* bo    = (const float*)d_in[8];
  const float* s1    = (const float*)d_in[9];
  const float* ln2_g = (const float*)d_in[10];
  const float* ln2_b = (const float*)d_in[11];
  const float* W1    = (const float*)d_in[12];
  const float* b1    = (const float*)d_in[13];
  const float* W2    = (const float*)d_in[14];
  const float* b2    = (const float*)d_in[15];
  const float* s2    = (const float*)d_in[16];
  float* xo = (float*)d_out;

  char* ws = (char*)d_ws;
  size_t off = 0;
  auto alloc = [&](size_t bytes) -> void* {
    void* p = ws + off;
    off += (bytes + 255) & ~(size_t)255;
    return p;
  };
  unsigned short* h_buf   = (unsigned short*)alloc((size_t)kRows * kDim * 2);
  unsigned short* qkv     = (unsigned short*)alloc((size_t)kRows * kQKV * 2);
  unsigned short* vT      = (unsigned short*)alloc((size_t)kB * kH * kDh * kN * 2);
  unsigned short* attnout = (unsigned short*)alloc((size_t)kRows * kDim * 2);
  unsigned short* mid     = (unsigned short*)alloc((size_t)kRows * kMlp * 2);
  unsigned short* wqkvT   = (unsigned short*)alloc((size_t)kQKV * kDim * 2);
  unsigned short* woT     = (unsigned short*)alloc((size_t)kDim * kDim * 2);
  unsigned short* w1T     = (unsigned short*)alloc((size_t)kMlp * kDim * 2);
  unsigned short* w2T     = (unsigned short*)alloc((size_t)kDim * kMlp * 2);

  size_t base = off;
  int IC = 1024;
  while (IC > 32 && base + (size_t)(kB * kH) * IC * kN * 4 + 1024 > ws_size) IC >>= 1;
  unsigned short* dots = (unsigned short*)alloc((size_t)(kB * kH) * IC * kN * 2);
  unsigned short* pbuf = (unsigned short*)alloc((size_t)(kB * kH) * IC * kN * 2);

  hipMemcpyAsync(xo, x, (size_t)kRows * kDim * 4, hipMemcpyDeviceToDevice, stream);

  for (int L = 0; L < kDepth; ++L) {
    // --- attention block ---
    ln_kernel<<<kRows, 256, 0, stream>>>(xo, ln1_g + L * kDim, ln1_b + L * kDim, h_buf);
    transpose_all<<<6912, 256, 0, stream>>>(Wq, Wkv, Wo, W1, W2, wqkvT, woT, w1T, w2T, L);

    gemm_kernel<0><<<dim3(kQKV / 128, kRows / 128), 256, 0, stream>>>(
        h_buf, wqkvT, nullptr, nullptr, nullptr, qkv, kDim, kQKV);
    transpose_v_kernel<<<dim3(kN / 32, kDh / 32, kB * kH), 256, 0, stream>>>(qkv, vT);

    for (int i0 = 0; i0 < kN; i0 += IC) {
      dots_kernel<<<dim3(kN / 32, IC / 32, kB), 256, 0, stream>>>(qkv, dots, i0, IC);
      softmax_mix_kernel<<<dim3(IC, kB), 256, 0, stream>>>(
          dots, pre + L * 144, post + L * 144, pbuf, IC);
      pv_kernel<<<dim3(IC / 32, kH, kB), 256, 0, stream>>>(pbuf, vT, attnout, i0, IC);
    }
    gemm_kernel<2><<<dim3(kDim / 128, kRows / 128), 256, 0, stream>>>(
        attnout, woT, bo + L * kDim, s1 + L * kDim, xo, nullptr, kDim, kDim);

    // --- MLP block ---
    ln_kernel<<<kRows, 256, 0, stream>>>(xo, ln2_g + L * kDim, ln2_b + L * kDim, h_buf);
    gemm_kernel<1><<<dim3(kMlp / 128, kRows / 128), 256, 0, stream>>>(
        h_buf, w1T, b1 + L * kMlp, nullptr, nullptr, mid, kDim, kMlp);
    gemm_kernel<2><<<dim3(kDim / 128, kRows / 128), 256, 0, stream>>>(
        mid, w2T, b2 + L * kDim, s2 + L * kDim, xo, nullptr, kMlp, kDim);
  }
}

// Round 7
// 3523.403 us; speedup vs baseline: 2.0639x; 1.2311x over previous
//
#include <hip/hip_runtime.h>

constexpr int kDepth = 6;
constexpr int kB = 8;
constexpr int kN = 1024;
constexpr int kDim = 768;
constexpr int kH = 12;
constexpr int kDh = 64;
constexpr int kMlp = 3072;
constexpr int kRows = kB * kN;   // 8192
constexpr int kQKV = 2304;       // q(768) k(768) v(768)

typedef __attribute__((ext_vector_type(4))) float f32x4;
typedef __attribute__((ext_vector_type(8))) short bf16x8;

__device__ __forceinline__ f32x4 mfma16x16x32(bf16x8 a, bf16x8 b, f32x4 c) {
  return __builtin_amdgcn_mfma_f32_16x16x32_bf16(a, b, c, 0, 0, 0);
}

__device__ __forceinline__ unsigned short f2bf(float f) {
  unsigned int u = __builtin_bit_cast(unsigned int, f);
  u = u + 0x7FFFu + ((u >> 16) & 1u);
  return (unsigned short)(u >> 16);
}

__device__ __forceinline__ float bf2f(unsigned short u) {
  return __builtin_bit_cast(float, (unsigned int)u << 16);
}

__device__ __forceinline__ void gload_lds16(const void* g, void* l) {
  __builtin_amdgcn_global_load_lds((__attribute__((address_space(1))) void*)g,
                                   (__attribute__((address_space(3))) void*)l,
                                   16, 0, 0);
}

// ---------------- LayerNorm: f32 in -> bf16 out ----------------
__global__ __launch_bounds__(256) void ln_kernel(const float* __restrict__ x,
                                                 const float* __restrict__ gamma,
                                                 const float* __restrict__ beta,
                                                 unsigned short* __restrict__ out) {
  int row = blockIdx.x, tid = threadIdx.x;
  const float* xr = x + (size_t)row * kDim;
  float v0 = xr[tid], v1 = xr[tid + 256], v2 = xr[tid + 512];
  float s = v0 + v1 + v2;
  float q = v0 * v0 + v1 * v1 + v2 * v2;
#pragma unroll
  for (int o = 32; o >= 1; o >>= 1) {
    s += __shfl_xor(s, o);
    q += __shfl_xor(q, o);
  }
  __shared__ float ss[4], sq[4];
  int wid = tid >> 6, lane = tid & 63;
  if (lane == 0) { ss[wid] = s; sq[wid] = q; }
  __syncthreads();
  s = ss[0] + ss[1] + ss[2] + ss[3];
  q = sq[0] + sq[1] + sq[2] + sq[3];
  float mean = s * (1.0f / kDim);
  float var = q * (1.0f / kDim) - mean * mean;
  float rstd = rsqrtf(var + 1e-5f);
  unsigned short* orow = out + (size_t)row * kDim;
  orow[tid]       = f2bf((v0 - mean) * rstd * gamma[tid]       + beta[tid]);
  orow[tid + 256] = f2bf((v1 - mean) * rstd * gamma[tid + 256] + beta[tid + 256]);
  orow[tid + 512] = f2bf((v2 - mean) * rstd * gamma[tid + 512] + beta[tid + 512]);
}

// ---------------- Batched weight transpose: all 5 matrices of one layer ----------------
__global__ __launch_bounds__(256) void transpose_all(const float* __restrict__ Wq,
                                                     const float* __restrict__ Wkv,
                                                     const float* __restrict__ Wo,
                                                     const float* __restrict__ W1,
                                                     const float* __restrict__ W2,
                                                     unsigned short* __restrict__ wqkvT,
                                                     unsigned short* __restrict__ woT,
                                                     unsigned short* __restrict__ w1T,
                                                     unsigned short* __restrict__ w2T,
                                                     int L) {
  int t = blockIdx.x;
  const float* src;
  unsigned short* dst;
  int R, C, dstOff;
  if (t < 576)       { src = Wq  + (size_t)L * 768 * 768;  R = 768;  C = 768;  dst = wqkvT; dstOff = 0;   }
  else if (t < 1728) { src = Wkv + (size_t)L * 768 * 1536; R = 768;  C = 1536; dst = wqkvT; dstOff = 768; t -= 576; }
  else if (t < 2304) { src = Wo  + (size_t)L * 768 * 768;  R = 768;  C = 768;  dst = woT;   dstOff = 0;   t -= 1728; }
  else if (t < 4608) { src = W1  + (size_t)L * 768 * 3072; R = 768;  C = 3072; dst = w1T;   dstOff = 0;   t -= 2304; }
  else               { src = W2  + (size_t)L * 3072 * 768; R = 3072; C = 768;  dst = w2T;   dstOff = 0;   t -= 4608; }
  int Ct = C >> 5;
  int bx = t % Ct, by = t / Ct;
  __shared__ float tt[32][33];
  int tx = threadIdx.x & 31, ty = threadIdx.x >> 5;  // ty 0..7
  int c0 = bx * 32, r0 = by * 32;
#pragma unroll
  for (int k = 0; k < 4; ++k) {
    int r = r0 + ty + k * 8;
    tt[ty + k * 8][tx] = src[(size_t)r * C + c0 + tx];
  }
  __syncthreads();
#pragma unroll
  for (int k = 0; k < 4; ++k) {
    int c = c0 + ty + k * 8;
    dst[(size_t)(dstOff + c) * R + r0 + tx] = f2bf(tt[tx][ty + k * 8]);
  }
}

// ---------------- V transpose: qkv[b,j,1536+g*64+d] -> vT[(b*12+g)*64+d][j] ----------------
__global__ __launch_bounds__(256) void transpose_v_kernel(const unsigned short* __restrict__ qkv,
                                                          unsigned short* __restrict__ vT) {
  __shared__ unsigned short t[32][33];
  int tx = threadIdx.x & 31, ty = threadIdx.x >> 5;
  int j0 = blockIdx.x * 32, d0 = blockIdx.y * 32;
  int bg = blockIdx.z;
  int b = bg / kH, g = bg % kH;
#pragma unroll
  for (int k = 0; k < 4; ++k) {
    int j = j0 + ty + k * 8;
    t[ty + k * 8][tx] = qkv[(size_t)(b * kN + j) * kQKV + 1536 + g * 64 + d0 + tx];
  }
  __syncthreads();
#pragma unroll
  for (int k = 0; k < 4; ++k) {
    int d = d0 + ty + k * 8;
    vT[((size_t)(b * kH + g) * kDh + d) * kN + j0 + tx] = t[tx][ty + k * 8];
  }
}

// ---------------- GEMM: A[M,K]bf16 x Bt[N,K]bf16 -> epilogue ----------------
// EPI 0: C=bf16 plain; EPI 1: bf16 gelu(acc+bias); EPI 2: resid = (acc+bias)*scl + resid (f32)
template <int EPI>
__global__ __launch_bounds__(256) void gemm_kernel(const unsigned short* __restrict__ A,
                                                   const unsigned short* __restrict__ Bt,
                                                   const float* __restrict__ bias,
                                                   const float* __restrict__ scl,
                                                   float* __restrict__ resid,
                                                   unsigned short* __restrict__ C,
                                                   int K, int ldc) {
  __shared__ __align__(16) unsigned short lA[128 * 64];
  __shared__ __align__(16) unsigned short lB[128 * 64];
  int tid = threadIdx.x, wid = tid >> 6, lane = tid & 63;
  // XCD-aware bijective chunked swizzle (all grids have nwg % 8 == 0)
  int gx = gridDim.x;
  int nwg = gx * gridDim.y;
  int orig = blockIdx.y * gx + blockIdx.x;
  int chunk = nwg >> 3;
  int wg = (orig & 7) * chunk + (orig >> 3);
  int bx = wg % gx, by = wg / gx;
  int row0 = by * 128, col0 = bx * 128;
  int wr = wid >> 1, wc = wid & 1;
  f32x4 zero = {0.f, 0.f, 0.f, 0.f};
  f32x4 acc[4][4];
#pragma unroll
  for (int m = 0; m < 4; ++m)
#pragma unroll
    for (int n = 0; n < 4; ++n) acc[m][n] = zero;

  for (int kt = 0; kt < K; kt += 64) {
    __syncthreads();
#pragma unroll
    for (int t = 0; t < 4; ++t) {
      int cbase = wid * 256 + t * 64;
      int c = cbase + lane;
      int r = c >> 3, slot = c & 7;
      int k8 = slot ^ (r & 7);  // source-swizzle so LDS holds XOR-swizzled layout
      gload_lds16(&A[(size_t)(row0 + r) * K + kt + k8 * 8], &lA[cbase * 8]);
      gload_lds16(&Bt[(size_t)(col0 + r) * K + kt + k8 * 8], &lB[cbase * 8]);
    }
    __syncthreads();
#pragma unroll
    for (int kk = 0; kk < 2; ++kk) {
      bf16x8 af[4], bfr[4];
      int kslot = kk * 4 + (lane >> 4);
#pragma unroll
      for (int m = 0; m < 4; ++m) {
        int r = wr * 64 + m * 16 + (lane & 15);
        af[m] = *reinterpret_cast<const bf16x8*>(&lA[r * 64 + ((kslot ^ (r & 7)) << 3)]);
      }
#pragma unroll
      for (int n = 0; n < 4; ++n) {
        int r = wc * 64 + n * 16 + (lane & 15);
        bfr[n] = *reinterpret_cast<const bf16x8*>(&lB[r * 64 + ((kslot ^ (r & 7)) << 3)]);
      }
#pragma unroll
      for (int m = 0; m < 4; ++m)
#pragma unroll
        for (int n = 0; n < 4; ++n) acc[m][n] = mfma16x16x32(af[m], bfr[n], acc[m][n]);
    }
  }
#pragma unroll
  for (int m = 0; m < 4; ++m)
#pragma unroll
    for (int n = 0; n < 4; ++n)
#pragma unroll
      for (int r4 = 0; r4 < 4; ++r4) {
        int row = row0 + wr * 64 + m * 16 + ((lane >> 4) << 2) + r4;
        int col = col0 + wc * 64 + n * 16 + (lane & 15);
        float v = acc[m][n][r4];
        if (EPI == 0) {
          C[(size_t)row * ldc + col] = f2bf(v);
        } else if (EPI == 1) {
          v += bias[col];
          v = 0.5f * v * (1.f + erff(v * 0.70710678118654752f));
          C[(size_t)row * ldc + col] = f2bf(v);
        } else {
          v = (v + bias[col]) * scl[col];
          size_t idx = (size_t)row * kDim + col;
          resid[idx] = resid[idx] + v;
        }
      }
}

// ---------------- QK^T raw per-head scores -> dots bf16, layout [b][i][j][h16] ----------------
// h slots 12..15 are zero. LDS-staged for fully coalesced dwordx4 global writes.
__global__ __launch_bounds__(256) void dots_kernel(const unsigned short* __restrict__ qkv,
                                                   unsigned short* __restrict__ dots,
                                                   int i0, int IC) {
  constexpr int TROW = 24;  // ushorts per (i,j) slot: 16 h + 8 pad (48B, 16B-aligned)
  __shared__ __align__(16) unsigned short T[32 * 32 * TROW];  // 48KB
  int tid = threadIdx.x, wid = tid >> 6, lane = tid & 63;
  int kg = lane >> 4, l15 = lane & 15;
  int j0 = blockIdx.x * 32;
  int il0 = blockIdx.y * 32;
  int b = blockIdx.z;
  // zero h-slots 12..15
  for (int idx = tid; idx < 2048; idx += 256) {
    int pos = idx >> 1;
    *(unsigned int*)&T[pos * TROW + 12 + (idx & 1) * 2] = 0u;
  }
  f32x4 zero = {0.f, 0.f, 0.f, 0.f};
#pragma unroll
  for (int rep = 0; rep < 3; ++rep) {
    int h = rep * 4 + wid;
    f32x4 acc[2][2];
    acc[0][0] = zero; acc[0][1] = zero; acc[1][0] = zero; acc[1][1] = zero;
#pragma unroll
    for (int kk = 0; kk < 2; ++kk) {
      bf16x8 aq[2], bk[2];
#pragma unroll
      for (int m = 0; m < 2; ++m) {
        int tok = i0 + il0 + m * 16 + l15;
        aq[m] = *reinterpret_cast<const bf16x8*>(
            &qkv[(size_t)(b * kN + tok) * kQKV + h * 64 + kk * 32 + kg * 8]);
      }
#pragma unroll
      for (int n = 0; n < 2; ++n) {
        int tj = j0 + n * 16 + l15;
        bk[n] = *reinterpret_cast<const bf16x8*>(
            &qkv[(size_t)(b * kN + tj) * kQKV + 768 + h * 64 + kk * 32 + kg * 8]);
      }
#pragma unroll
      for (int m = 0; m < 2; ++m)
#pragma unroll
        for (int n = 0; n < 2; ++n) acc[m][n] = mfma16x16x32(aq[m], bk[n], acc[m][n]);
    }
#pragma unroll
    for (int m = 0; m < 2; ++m)
#pragma unroll
      for (int n = 0; n < 2; ++n)
#pragma unroll
        for (int r = 0; r < 4; ++r)
          T[((m * 16 + kg * 4 + r) * 32 + n * 16 + l15) * TROW + h] = f2bf(acc[m][n][r]);
  }
  __syncthreads();
  // coalesced write-out: 2048 chunks of 16B
#pragma unroll
  for (int k = 0; k < 8; ++k) {
    int c = tid + k * 256;
    int pos = c >> 1, half = c & 1;
    int ii = pos >> 5, jj = pos & 31;
    *(f32x4*)&dots[((size_t)(b * IC + il0 + ii) * kN + j0 + jj) * 16 + half * 8] =
        *(const f32x4*)&T[pos * TROW + half * 8];
  }
}

// ---------------- MFMA premix + softmax (no-max+clamp) + MFMA postmix -> p bf16 ----------------
// dots layout [b][i][j][h16]; pbuf layout [b][g2][i][j] (unchanged for pv).
__global__ __launch_bounds__(256) void softmax_mix_kernel(const unsigned short* __restrict__ dots,
                                                          const float* __restrict__ pre,
                                                          const float* __restrict__ post,
                                                          unsigned short* __restrict__ pbuf,
                                                          int IC) {
  constexpr int EROW = 24;  // ushorts per j row of E (16 g + 8 pad, 16B-aligned)
  __shared__ __align__(16) unsigned short E[1024 * EROW];   // 48KB
  __shared__ __align__(16) unsigned short preA[16 * 32];
  __shared__ __align__(16) unsigned short postA[16 * 32];
  __shared__ float red[4][16];
  __shared__ float lgs[16];
  int tid = threadIdx.x, wid = tid >> 6, lane = tid & 63;
  int kg = lane >> 4, l15 = lane & 15;
  int i = blockIdx.x, b = blockIdx.y;
  // build preA[m=g][k=h] = pre[h][g] * 0.125, zero-padded
  for (int idx = tid; idx < 512; idx += 256) {
    int m = idx >> 5, k = idx & 31;
    preA[idx] = f2bf((m < 12 && k < 12) ? pre[k * 12 + m] * 0.125f : 0.f);
  }
  __syncthreads();
  bf16x8 preF = *(const bf16x8*)&preA[l15 * 32 + kg * 8];
  const unsigned short* drow = dots + (size_t)(b * IC + i) * kN * 16;
  f32x4 zero = {0.f, 0.f, 0.f, 0.f};
  bf16x8 zfrag = {0, 0, 0, 0, 0, 0, 0, 0};
  float psum[4] = {0.f, 0.f, 0.f, 0.f};
  // pass A: premix via MFMA, exp, stash E[j][g], accumulate psum
#pragma unroll
  for (int grp = 0; grp < 16; ++grp) {
    int j = wid * 256 + grp * 16 + l15;
    bf16x8 bfrag = (kg < 2) ? *(const bf16x8*)&drow[(size_t)j * 16 + kg * 8] : zfrag;
    f32x4 d = mfma16x16x32(preF, bfrag, zero);  // D[g=kg*4+r][j=l15]
    float ee[4];
#pragma unroll
    for (int r = 0; r < 4; ++r) {
      float dc = fminf(fmaxf(d[r], -15.f), 15.f);
      ee[r] = (kg == 3) ? 0.f : __expf(dc);
      psum[r] += ee[r];
    }
    unsigned int w0, w1;
    asm("v_cvt_pk_bf16_f32 %0, %1, %2" : "=v"(w0) : "v"(ee[0]), "v"(ee[1]));
    asm("v_cvt_pk_bf16_f32 %0, %1, %2" : "=v"(w1) : "v"(ee[2]), "v"(ee[3]));
    *(unsigned int*)&E[j * EROW + kg * 4] = w0;
    *(unsigned int*)&E[j * EROW + kg * 4 + 2] = w1;
  }
  // reduce psum over 16 cols (l15 lanes), then 4 waves
#pragma unroll
  for (int r = 0; r < 4; ++r) {
    psum[r] += __shfl_xor(psum[r], 1);
    psum[r] += __shfl_xor(psum[r], 2);
    psum[r] += __shfl_xor(psum[r], 4);
    psum[r] += __shfl_xor(psum[r], 8);
  }
  if (l15 == 0) {
#pragma unroll
    for (int r = 0; r < 4; ++r) red[wid][kg * 4 + r] = psum[r];
  }
  __syncthreads();
  if (tid < 16) {
    float s = red[0][tid] + red[1][tid] + red[2][tid] + red[3][tid];
    lgs[tid] = (tid < 12) ? 1.f / s : 0.f;
  }
  __syncthreads();
  // build postA[m=g2][k=g] = post[g][g2] * lg[g], zero-padded
  for (int idx = tid; idx < 512; idx += 256) {
    int m = idx >> 5, k = idx & 31;
    postA[idx] = f2bf((m < 12 && k < 12) ? post[k * 12 + m] * lgs[k] : 0.f);
  }
  __syncthreads();
  bf16x8 postF = *(const bf16x8*)&postA[l15 * 32 + kg * 8];
  // pass B: postmix via MFMA, write p
#pragma unroll
  for (int grp = 0; grp < 16; ++grp) {
    int j = wid * 256 + grp * 16 + l15;
    bf16x8 efrag = (kg < 2) ? *(const bf16x8*)&E[j * EROW + kg * 8] : zfrag;
    f32x4 d2 = mfma16x16x32(postF, efrag, zero);  // D[g2=kg*4+r][j=l15]
    if (kg < 3) {
#pragma unroll
      for (int r = 0; r < 4; ++r) {
        int g2 = kg * 4 + r;
        pbuf[((size_t)(b * kH + g2) * IC + i) * kN + j] = f2bf(d2[r]);
      }
    }
  }
}

// ---------------- PV: out[b,i,g*64+d] = sum_j p[b,g,i,j] * v[b,g,j,d] (32 i-rows/block) --------
__global__ __launch_bounds__(256) void pv_kernel(const unsigned short* __restrict__ pbuf,
                                                 const unsigned short* __restrict__ vT,
                                                 unsigned short* __restrict__ attn_out,
                                                 int i0, int IC) {
  int tid = threadIdx.x, wid = tid >> 6, lane = tid & 63;
  int kg = lane >> 4, l15 = lane & 15;
  int i32 = blockIdx.x * 32;
  int g = blockIdx.y, b = blockIdx.z;
  const unsigned short* prow = pbuf + (size_t)(b * kH + g) * IC * kN;
  const unsigned short* vrow = vT + (size_t)(b * kH + g) * kDh * kN;
  f32x4 zero = {0.f, 0.f, 0.f, 0.f};
  f32x4 acc[2][4];
#pragma unroll
  for (int half = 0; half < 2; ++half)
#pragma unroll
    for (int n = 0; n < 4; ++n) acc[half][n] = zero;
#pragma unroll
  for (int s = 0; s < 8; ++s) {
    int kt = (wid * 8 + s) * 32 + kg * 8;
    bf16x8 ap[2];
#pragma unroll
    for (int half = 0; half < 2; ++half)
      ap[half] = *reinterpret_cast<const bf16x8*>(&prow[(size_t)(i32 + half * 16 + l15) * kN + kt]);
#pragma unroll
    for (int n = 0; n < 4; ++n) {
      bf16x8 bv = *reinterpret_cast<const bf16x8*>(&vrow[(size_t)(n * 16 + l15) * kN + kt]);
#pragma unroll
      for (int half = 0; half < 2; ++half)
        acc[half][n] = mfma16x16x32(ap[half], bv, acc[half][n]);
    }
  }
  __shared__ float red[3][32][64];
  if (wid > 0) {
#pragma unroll
    for (int half = 0; half < 2; ++half)
#pragma unroll
      for (int n = 0; n < 4; ++n)
#pragma unroll
        for (int r = 0; r < 4; ++r)
          red[wid - 1][half * 16 + kg * 4 + r][n * 16 + l15] = acc[half][n][r];
  }
  __syncthreads();
  if (wid == 0) {
#pragma unroll
    for (int half = 0; half < 2; ++half)
#pragma unroll
      for (int n = 0; n < 4; ++n)
#pragma unroll
        for (int r = 0; r < 4; ++r) {
          int rr = half * 16 + kg * 4 + r, cc = n * 16 + l15;
          float v = acc[half][n][r] + red[0][rr][cc] + red[1][rr][cc] + red[2][rr][cc];
          int tok = i0 + i32 + rr;
          attn_out[(size_t)(b * kN + tok) * kDim + g * kDh + cc] = f2bf(v);
        }
  }
}

extern "C" void kernel_launch(void* const* d_in, const int* in_sizes, int n_in,
                              void* d_out, int out_size, void* d_ws, size_t ws_size,
                              hipStream_t stream) {
  (void)in_sizes; (void)n_in; (void)out_size;
  const float* x     = (const float*)d_in[0];
  const float* ln1_g = (const float*)d_in[1];
  const float* ln1_b = (const float*)d_in[2];
  const float* Wq    = (const float*)d_in[3];
  const float* Wkv   = (const float*)d_in[4];
  const float* pre   = (const float*)d_in[5];
  const float* post  = (const float*)d_in[6];
  const float* Wo    = (const float*)d_in[7];
  const float* bo    = (const float*)d_in[8];
  const float* s1    = (const float*)d_in[9];
  const float* ln2_g = (const float*)d_in[10];
  const float* ln2_b = (const float*)d_in[11];
  const float* W1    = (const float*)d_in[12];
  const float* b1    = (const float*)d_in[13];
  const float* W2    = (const float*)d_in[14];
  const float* b2    = (const float*)d_in[15];
  const float* s2    = (const float*)d_in[16];
  float* xo = (float*)d_out;

  char* ws = (char*)d_ws;
  size_t off = 0;
  auto alloc = [&](size_t bytes) -> void* {
    void* p = ws + off;
    off += (bytes + 255) & ~(size_t)255;
    return p;
  };
  unsigned short* h_buf   = (unsigned short*)alloc((size_t)kRows * kDim * 2);
  unsigned short* qkv     = (unsigned short*)alloc((size_t)kRows * kQKV * 2);
  unsigned short* vT      = (unsigned short*)alloc((size_t)kB * kH * kDh * kN * 2);
  unsigned short* attnout = (unsigned short*)alloc((size_t)kRows * kDim * 2);
  unsigned short* mid     = (unsigned short*)alloc((size_t)kRows * kMlp * 2);
  unsigned short* wqkvT   = (unsigned short*)alloc((size_t)kQKV * kDim * 2);
  unsigned short* woT     = (unsigned short*)alloc((size_t)kDim * kDim * 2);
  unsigned short* w1T     = (unsigned short*)alloc((size_t)kMlp * kDim * 2);
  unsigned short* w2T     = (unsigned short*)alloc((size_t)kDim * kMlp * 2);

  size_t base = off;
  // per-i-row bytes: dots [b][i][j][16] bf16 = 8*1024*16*2 = 262144; pbuf = 8*12*1024*2 = 196608
  int IC = 1024;
  while (IC > 32 && base + (size_t)IC * (262144 + 196608) + 1024 > ws_size) IC >>= 1;
  unsigned short* dots = (unsigned short*)alloc((size_t)kB * IC * kN * 16 * 2);
  unsigned short* pbuf = (unsigned short*)alloc((size_t)kB * kH * IC * kN * 2);

  hipMemcpyAsync(xo, x, (size_t)kRows * kDim * 4, hipMemcpyDeviceToDevice, stream);

  for (int L = 0; L < kDepth; ++L) {
    // --- attention block ---
    ln_kernel<<<kRows, 256, 0, stream>>>(xo, ln1_g + L * kDim, ln1_b + L * kDim, h_buf);
    transpose_all<<<6912, 256, 0, stream>>>(Wq, Wkv, Wo, W1, W2, wqkvT, woT, w1T, w2T, L);

    gemm_kernel<0><<<dim3(kQKV / 128, kRows / 128), 256, 0, stream>>>(
        h_buf, wqkvT, nullptr, nullptr, nullptr, qkv, kDim, kQKV);
    transpose_v_kernel<<<dim3(kN / 32, kDh / 32, kB * kH), 256, 0, stream>>>(qkv, vT);

    for (int i0 = 0; i0 < kN; i0 += IC) {
      dots_kernel<<<dim3(kN / 32, IC / 32, kB), 256, 0, stream>>>(qkv, dots, i0, IC);
      softmax_mix_kernel<<<dim3(IC, kB), 256, 0, stream>>>(
          dots, pre + L * 144, post + L * 144, pbuf, IC);
      pv_kernel<<<dim3(IC / 32, kH, kB), 256, 0, stream>>>(pbuf, vT, attnout, i0, IC);
    }
    gemm_kernel<2><<<dim3(kDim / 128, kRows / 128), 256, 0, stream>>>(
        attnout, woT, bo + L * kDim, s1 + L * kDim, xo, nullptr, kDim, kDim);

    // --- MLP block ---
    ln_kernel<<<kRows, 256, 0, stream>>>(xo, ln2_g + L * kDim, ln2_b + L * kDim, h_buf);
    gemm_kernel<1><<<dim3(kMlp / 128, kRows / 128), 256, 0, stream>>>(
        h_buf, w1T, b1 + L * kMlp, nullptr, nullptr, mid, kDim, kMlp);
    gemm_kernel<2><<<dim3(kDim / 128, kRows / 128), 256, 0, stream>>>(
        mid, w2T, b2 + L * kDim, s2 + L * kDim, xo, nullptr, kMlp, kDim);
  }
}